// Round 4
// baseline (967.847 us; speedup 1.0000x reference)
//
#include <hip/hip_runtime.h>
#include <math.h>

// Problem dims (fixed by setup_inputs)
#define BB 8
#define CC 256
#define HWHW 4096            // 64*64
#define NN 32768             // BB*HWHW
#define KD 1024
#define C2 512

// ---------------- workspace layout (float offsets) ----------------
// xo is written directly into d_out's `out` region (k_conv is in-place per
// plane), so no OFF_XOT buffer. Total ws use: ~74 MB.
#define OFF_XF     0u           // N*C  = 8388608   x in (n,c) layout
#define OFF_GT     8388608u     // N*C              g in (b,c,hw) layout
#define OFF_RNORM  16777216u    // N                1/||xf row||
#define OFF_P      16809984u    // C                p = 1+4*sigmoid(power)
#define OFF_MN0    16810240u    // K*C              l2norm(units_w)
#define OFF_MNEW   17072384u    // K*C              EMA-updated codebook
#define OFF_SUMS   17334528u    // K*C   (zeroed)
#define OFF_COUNTS 17596672u    // K     (zeroed)
#define OFF_KMEAN  17597696u    // 2C    (zeroed)
#define OFF_KVBIG  17598208u    // 512*256 (zeroed) fused [kv | shifted kv2]
#define OFF_Z      17729280u    // N
#define OFF_Z2     17762048u    // N
#define OFF_IND    17794816u    // N ints
#define OFF_KK     17827584u    // K*2C = 524288    power features of codebook
#define ZERO_CNT   394752u      // SUMS..KVBIG contiguous

__device__ __forceinline__ float wredsum(float v) {
#pragma unroll
  for (int o = 32; o; o >>= 1) v += __shfl_xor(v, o);
  return v;
}

// p = 1 + 4*sigmoid(power)
__global__ void k_prep(const float* __restrict__ power, float* __restrict__ p) {
  int i = threadIdx.x;
  p[i] = 1.0f + 4.0f / (1.0f + expf(-power[i]));
}

__global__ void k_zero(float* __restrict__ zr) {
  unsigned i = blockIdx.x * 256u + threadIdx.x;
  if (i < ZERO_CNT) zr[i] = 0.0f;
}

// x (b,c,hw) -> xf (b*hw, c)
__global__ void k_transpose(const float* __restrict__ x, float* __restrict__ xf) {
  __shared__ float tile[32][33];
  int b = blockIdx.z, hw0 = blockIdx.x * 32, c0 = blockIdx.y * 32;
  int tx = threadIdx.x, ty = threadIdx.y;
#pragma unroll
  for (int i = 0; i < 32; i += 8)
    tile[ty + i][tx] = x[(size_t)(b * CC + c0 + ty + i) * HWHW + hw0 + tx];
  __syncthreads();
#pragma unroll
  for (int i = 0; i < 32; i += 8)
    xf[(size_t)(b * HWHW + hw0 + ty + i) * CC + c0 + tx] = tile[tx][ty + i];
}

// per-row 1/max(||row||, eps), one wave per row
__global__ void k_rownorm(const float* __restrict__ xf, float* __restrict__ rnorm) {
  int wv = threadIdx.x >> 6, ln = threadIdx.x & 63;
  int row = blockIdx.x * 4 + wv;
  float4 v = *(const float4*)(xf + (size_t)row * CC + ln * 4);
  float ss = wredsum(v.x * v.x + v.y * v.y + v.z * v.z + v.w * v.w);
  if (ln == 0) rnorm[row] = 1.0f / fmaxf(sqrtf(ss), 1e-12f);
}

// mn0 = l2norm(units_w) rows, one wave per row
__global__ void k_mnorm(const float* __restrict__ uw, float* __restrict__ mn0) {
  int wv = threadIdx.x >> 6, ln = threadIdx.x & 63;
  int row = blockIdx.x * 4 + wv;
  float4 v = *(const float4*)(uw + (size_t)row * CC + ln * 4);
  float ss = wredsum(v.x * v.x + v.y * v.y + v.z * v.z + v.w * v.w);
  float rn = 1.0f / fmaxf(sqrtf(ss), 1e-12f);
  float4 o = {v.x * rn, v.y * rn, v.z * rn, v.w * rn};
  *(float4*)(mn0 + (size_t)row * CC + ln * 4) = o;
}

// score = (xf*rnorm) @ mn0^T   (N x KD, K-dim = C)
__global__ __launch_bounds__(256) void k_score(const float* __restrict__ xf,
                                               const float* __restrict__ rnorm,
                                               const float* __restrict__ mn0,
                                               float* __restrict__ score) {
  __shared__ float As[32][132];
  __shared__ float Bs[32][132];
  int t = threadIdx.x;
  int row0 = blockIdx.x * 128, col0 = blockIdx.y * 128;
  int kc = t & 7, lr = t >> 3;                 // loader: 8 k-chunks x 32 rows
  int fr = (t & 15) * 4, fc = ((t >> 4) & 15) * 4;
  float rnA[4];
#pragma unroll
  for (int ps = 0; ps < 4; ps++) rnA[ps] = rnorm[row0 + lr + ps * 32];
  float acc[8][8] = {};
  for (int k0 = 0; k0 < CC; k0 += 32) {
    __syncthreads();
#pragma unroll
    for (int ps = 0; ps < 4; ps++) {
      int r = lr + ps * 32;
      float4 v = *(const float4*)(xf + (size_t)(row0 + r) * CC + k0 + kc * 4);
      float rn = rnA[ps];
      As[kc * 4 + 0][r] = v.x * rn; As[kc * 4 + 1][r] = v.y * rn;
      As[kc * 4 + 2][r] = v.z * rn; As[kc * 4 + 3][r] = v.w * rn;
      float4 w = *(const float4*)(mn0 + (size_t)(col0 + r) * CC + k0 + kc * 4);
      Bs[kc * 4 + 0][r] = w.x; Bs[kc * 4 + 1][r] = w.y;
      Bs[kc * 4 + 2][r] = w.z; Bs[kc * 4 + 3][r] = w.w;
    }
    __syncthreads();
#pragma unroll
    for (int kk = 0; kk < 32; kk++) {
      float4 a0 = *(const float4*)&As[kk][fr];
      float4 a1 = *(const float4*)&As[kk][64 + fr];
      float4 b0 = *(const float4*)&Bs[kk][fc];
      float4 b1 = *(const float4*)&Bs[kk][64 + fc];
      float av[8] = {a0.x, a0.y, a0.z, a0.w, a1.x, a1.y, a1.z, a1.w};
      float bv[8] = {b0.x, b0.y, b0.z, b0.w, b1.x, b1.y, b1.z, b1.w};
#pragma unroll
      for (int i = 0; i < 8; i++)
#pragma unroll
        for (int j = 0; j < 8; j++) acc[i][j] += av[i] * bv[j];
    }
  }
#pragma unroll
  for (int i = 0; i < 8; i++) {
    int row = row0 + (i < 4 ? fr + i : 64 + fr + i - 4);
    float4 o0 = {acc[i][0], acc[i][1], acc[i][2], acc[i][3]};
    float4 o1 = {acc[i][4], acc[i][5], acc[i][6], acc[i][7]};
    *(float4*)(score + (size_t)row * KD + col0 + fc) = o0;
    *(float4*)(score + (size_t)row * KD + col0 + 64 + fc) = o1;
  }
}

// g = xf @ g_w^T + g_b, stored transposed to (b,c,hw)
__global__ __launch_bounds__(256) void k_g(const float* __restrict__ xf,
                                           const float* __restrict__ gw,
                                           const float* __restrict__ gb,
                                           float* __restrict__ gt) {
  __shared__ float As[32][132];
  __shared__ float Bs[32][132];
  int t = threadIdx.x;
  int row0 = blockIdx.x * 128, col0 = blockIdx.y * 128;
  int kc = t & 7, lr = t >> 3;
  int fr = (t & 15) * 4, fc = ((t >> 4) & 15) * 4;
  float acc[8][8] = {};
  for (int k0 = 0; k0 < CC; k0 += 32) {
    __syncthreads();
#pragma unroll
    for (int ps = 0; ps < 4; ps++) {
      int r = lr + ps * 32;
      float4 v = *(const float4*)(xf + (size_t)(row0 + r) * CC + k0 + kc * 4);
      As[kc * 4 + 0][r] = v.x; As[kc * 4 + 1][r] = v.y;
      As[kc * 4 + 2][r] = v.z; As[kc * 4 + 3][r] = v.w;
      float4 w = *(const float4*)(gw + (size_t)(col0 + r) * CC + k0 + kc * 4);
      Bs[kc * 4 + 0][r] = w.x; Bs[kc * 4 + 1][r] = w.y;
      Bs[kc * 4 + 2][r] = w.z; Bs[kc * 4 + 3][r] = w.w;
    }
    __syncthreads();
#pragma unroll
    for (int kk = 0; kk < 32; kk++) {
      float4 a0 = *(const float4*)&As[kk][fr];
      float4 a1 = *(const float4*)&As[kk][64 + fr];
      float4 b0 = *(const float4*)&Bs[kk][fc];
      float4 b1 = *(const float4*)&Bs[kk][64 + fc];
      float av[8] = {a0.x, a0.y, a0.z, a0.w, a1.x, a1.y, a1.z, a1.w};
      float bv[8] = {b0.x, b0.y, b0.z, b0.w, b1.x, b1.y, b1.z, b1.w};
#pragma unroll
      for (int i = 0; i < 8; i++)
#pragma unroll
        for (int j = 0; j < 8; j++) acc[i][j] += av[i] * bv[j];
    }
  }
#pragma unroll
  for (int i = 0; i < 8; i++) {
    int row = row0 + (i < 4 ? fr + i : 64 + fr + i - 4);
    int b = row >> 12, hw = row & 4095;
#pragma unroll
    for (int j = 0; j < 8; j++) {
      int col = col0 + (j < 4 ? fc + j : 64 + fc + j - 4);
      gt[(size_t)(b * CC + col) * HWHW + hw] = acc[i][j] + gb[col];
    }
  }
}

// argmax over each score row (first max wins), one wave per row
__global__ void k_argmax(const float* __restrict__ score, int* __restrict__ ind) {
  int wv = threadIdx.x >> 6, ln = threadIdx.x & 63;
  int row = blockIdx.x * 4 + wv;
  const float* r = score + (size_t)row * KD;
  float best = -3.4e38f; int bi = 0;
#pragma unroll
  for (int ch = 0; ch < 4; ch++) {
    int base = ln * 16 + ch * 4;
    float4 v = *(const float4*)(r + base);
    float vv[4] = {v.x, v.y, v.z, v.w};
#pragma unroll
    for (int j = 0; j < 4; j++) {
      float val = vv[j]; int idx = base + j;
      if (val > best || (val == best && idx < bi)) { best = val; bi = idx; }
    }
  }
#pragma unroll
  for (int o = 32; o; o >>= 1) {
    float ov = __shfl_xor(best, o); int oi = __shfl_xor(bi, o);
    if (ov > best || (ov == best && oi < bi)) { best = ov; bi = oi; }
  }
  if (ln == 0) ind[row] = bi;
}

// scatter-add rows of xf into sums[ind], one wave per row
__global__ void k_scatter(const float* __restrict__ xf, const int* __restrict__ ind,
                          float* __restrict__ sums, float* __restrict__ counts) {
  int wv = threadIdx.x >> 6, ln = threadIdx.x & 63;
  int row = blockIdx.x * 4 + wv;
  int j = ind[row];
  const float* xr = xf + (size_t)row * CC;
  float* sb = sums + (size_t)j * CC;
#pragma unroll
  for (int c = 0; c < CC; c += 64) atomicAdd(&sb[c + ln], xr[c + ln]);
  if (ln == 0) atomicAdd(&counts[j], 1.0f);
}

// EMA update + normalized-power features kk + kmean accumulation. Wave per row.
__global__ void k_ema(const float* __restrict__ uw, const float* __restrict__ sums,
                      const float* __restrict__ counts, const float* __restrict__ p,
                      float* __restrict__ mnew, float* __restrict__ kkb,
                      float* __restrict__ kmean) {
  int wv = threadIdx.x >> 6, ln = threadIdx.x & 63;
  int j = blockIdx.x * 4 + wv;
  int c = ln * 4;
  float cnt = counts[j] + 1e-6f;
  float4 s4 = *(const float4*)(sums + (size_t)j * CC + c);
  float4 u4 = *(const float4*)(uw + (size_t)j * CC + c);
  float4 m4;
  m4.x = u4.x * 0.999f + (s4.x / cnt) * 0.001f;
  m4.y = u4.y * 0.999f + (s4.y / cnt) * 0.001f;
  m4.z = u4.z * 0.999f + (s4.z / cnt) * 0.001f;
  m4.w = u4.w * 0.999f + (s4.w / cnt) * 0.001f;
  *(float4*)(mnew + (size_t)j * CC + c) = m4;
  float ss = wredsum(m4.x * m4.x + m4.y * m4.y + m4.z * m4.z + m4.w * m4.w);
  float rn = 1.0f / fmaxf(sqrtf(ss), 1e-12f);
  float4 p4 = *(const float4*)(p + c);
  float mv[4] = {m4.x * rn, m4.y * rn, m4.z * rn, m4.w * rn};
  float pv[4] = {p4.x, p4.y, p4.z, p4.w};
  float kp[4], kn[4];
#pragma unroll
  for (int i = 0; i < 4; i++) {
    kp[i] = mv[i] > 0.0f ? powf(mv[i], pv[i]) : 0.0f;
    kn[i] = (-mv[i]) > 0.0f ? powf(-mv[i], pv[i]) : 0.0f;
  }
  float4 kp4 = {kp[0], kp[1], kp[2], kp[3]};
  float4 kn4 = {kn[0], kn[1], kn[2], kn[3]};
  *(float4*)(kkb + (size_t)j * C2 + c) = kp4;
  *(float4*)(kkb + (size_t)j * C2 + 256 + c) = kn4;
#pragma unroll
  for (int i = 0; i < 4; i++) {
    atomicAdd(&kmean[c + i], kp[i]);
    atomicAdd(&kmean[256 + c + i], kn[i]);
  }
}

__global__ void k_kmean_fin(float* __restrict__ kmean) {
  int i = blockIdx.x * 256 + threadIdx.x;
  if (i < C2) kmean[i] *= (1.0f / 1024.0f);
}

// kv_all = kk^T @ mnew / n, written into fused KVbig layout:
// KVbig[t][c] = c<128 ? kv[t][c] : kv2[(t+256)&511][c-128]
__global__ __launch_bounds__(256) void k_kv(const float* __restrict__ kkb,
                                            const float* __restrict__ mnew,
                                            float* __restrict__ kvbig) {
  __shared__ float Ks[32][64];
  __shared__ float Ms[32][64];
  int t = threadIdx.x;
  int t0 = blockIdx.x * 64, c0 = blockIdx.y * 64, kbase = blockIdx.z * 128;
  int cl4 = (t & 15) * 4, kr = t >> 4;
  int fr = (t & 15) * 4, fc = ((t >> 4) & 15) * 4;
  float acc[4][4] = {};
  for (int k0 = kbase; k0 < kbase + 128; k0 += 32) {
    __syncthreads();
#pragma unroll
    for (int ps = 0; ps < 2; ps++) {
      int kr2 = kr + ps * 16;
      *(float4*)&Ks[kr2][cl4] = *(const float4*)(kkb + (size_t)(k0 + kr2) * C2 + t0 + cl4);
      *(float4*)&Ms[kr2][cl4] = *(const float4*)(mnew + (size_t)(k0 + kr2) * CC + c0 + cl4);
    }
    __syncthreads();
#pragma unroll
    for (int kx = 0; kx < 32; kx++) {
      float4 a = *(const float4*)&Ks[kx][fr];
      float4 b = *(const float4*)&Ms[kx][fc];
      float av[4] = {a.x, a.y, a.z, a.w}, bv[4] = {b.x, b.y, b.z, b.w};
#pragma unroll
      for (int i = 0; i < 4; i++)
#pragma unroll
        for (int j = 0; j < 4; j++) acc[i][j] += av[i] * bv[j];
    }
  }
  const float sc = 1.0f / 32768.0f;
#pragma unroll
  for (int i = 0; i < 4; i++) {
    int tt = t0 + fr + i;
#pragma unroll
    for (int j = 0; j < 4; j++) {
      int c = c0 + fc + j;
      int drow = (c < 128) ? tt : ((tt + 256) & 511);
      atomicAdd(&kvbig[(size_t)drow * CC + c], acc[i][j] * sc);
    }
  }
}

// z = 1/(q_sim . kmean + eps), z2 = 1/(q_opp . kmean + eps). Wave per row.
__global__ void k_z(const float* __restrict__ xf, const float* __restrict__ rnorm,
                    const float* __restrict__ p, const float* __restrict__ kmean,
                    float* __restrict__ z, float* __restrict__ z2) {
  int wv = threadIdx.x >> 6, ln = threadIdx.x & 63;
  int row = blockIdx.x * 4 + wv;
  int c = ln * 4;
  float rn = rnorm[row];
  float4 v = *(const float4*)(xf + (size_t)row * CC + c);
  float4 p4 = *(const float4*)(p + c);
  float4 k0 = *(const float4*)(kmean + c);
  float4 k1 = *(const float4*)(kmean + 256 + c);
  float xv[4] = {v.x * rn, v.y * rn, v.z * rn, v.w * rn};
  float pv[4] = {p4.x, p4.y, p4.z, p4.w};
  float ka[4] = {k0.x, k0.y, k0.z, k0.w};
  float kb[4] = {k1.x, k1.y, k1.z, k1.w};
  float za = 0.0f, zb = 0.0f;
#pragma unroll
  for (int i = 0; i < 4; i++) {
    float qp = xv[i] > 0.0f ? powf(xv[i], pv[i]) : 0.0f;
    float qn = (-xv[i]) > 0.0f ? powf(-xv[i], pv[i]) : 0.0f;
    za += qp * ka[i] + qn * kb[i];
    zb += qn * ka[i] + qp * kb[i];
  }
  za = wredsum(za); zb = wredsum(zb);
  if (ln == 0) { z[row] = 1.0f / (za + 1e-6f); z2[row] = 1.0f / (zb + 1e-6f); }
}

// xo = (Q @ KVbig) * [z|z2], stored transposed to (b,c,hw) directly in d_out.
__global__ __launch_bounds__(256) void k_x(const float* __restrict__ xf,
                                           const float* __restrict__ rnorm,
                                           const float* __restrict__ p,
                                           const float* __restrict__ kvbig,
                                           const float* __restrict__ z,
                                           const float* __restrict__ z2,
                                           float* __restrict__ xot) {
  __shared__ float As[32][132];
  __shared__ float Bs[32][128];
  int t = threadIdx.x;
  int row0 = blockIdx.x * 128, col0 = blockIdx.y * 128;
  int kc = t & 7, lr = t >> 3;
  int bc4 = (t & 31) * 4, bk = t >> 5;
  int fr = (t & 15) * 4, fc = ((t >> 4) & 15) * 4;
  float rnA[4];
#pragma unroll
  for (int ps = 0; ps < 4; ps++) rnA[ps] = rnorm[row0 + lr + ps * 32];
  float acc[8][8] = {};
  for (int k0 = 0; k0 < C2; k0 += 32) {
    bool negh = (k0 >= 256);
    int cb = (k0 & 255) + kc * 4;
    __syncthreads();
#pragma unroll
    for (int ps = 0; ps < 4; ps++) {
      int r = lr + ps * 32;
      float4 v = *(const float4*)(xf + (size_t)(row0 + r) * CC + cb);
      float4 p4 = *(const float4*)(p + cb);
      float rn = rnA[ps];
      float xv[4] = {v.x * rn, v.y * rn, v.z * rn, v.w * rn};
      float pv[4] = {p4.x, p4.y, p4.z, p4.w};
#pragma unroll
      for (int jj = 0; jj < 4; jj++) {
        float b = negh ? -xv[jj] : xv[jj];
        As[kc * 4 + jj][r] = b > 0.0f ? powf(b, pv[jj]) : 0.0f;
      }
      int krow = bk + ps * 8;
      *(float4*)&Bs[krow][bc4] =
          *(const float4*)(kvbig + (size_t)(k0 + krow) * CC + col0 + bc4);
    }
    __syncthreads();
#pragma unroll
    for (int kk = 0; kk < 32; kk++) {
      float4 a0 = *(const float4*)&As[kk][fr];
      float4 a1 = *(const float4*)&As[kk][64 + fr];
      float4 b0 = *(const float4*)&Bs[kk][fc];
      float4 b1 = *(const float4*)&Bs[kk][64 + fc];
      float av[8] = {a0.x, a0.y, a0.z, a0.w, a1.x, a1.y, a1.z, a1.w};
      float bv[8] = {b0.x, b0.y, b0.z, b0.w, b1.x, b1.y, b1.z, b1.w};
#pragma unroll
      for (int i = 0; i < 8; i++)
#pragma unroll
        for (int j = 0; j < 8; j++) acc[i][j] += av[i] * bv[j];
    }
  }
  const float* zz = (col0 == 0) ? z : z2;
#pragma unroll
  for (int i = 0; i < 8; i++) {
    int row = row0 + (i < 4 ? fr + i : 64 + fr + i - 4);
    int b = row >> 12, hw = row & 4095;
    float zs = zz[row];
#pragma unroll
    for (int j = 0; j < 8; j++) {
      int col = col0 + (j < 4 ? fc + j : 64 + fc + j - 4);
      xot[(size_t)(b * CC + col) * HWHW + hw] = acc[i][j] * zs;
    }
  }
}

// out = (xo + dwconv3x3(xo) + bias) * g, IN-PLACE on d_out per (b,ch) plane.
// Safe: each block loads its entire plane to LDS, syncs, then overwrites it;
// blocks touch disjoint planes.
__global__ __launch_bounds__(256) void k_conv(float* __restrict__ out,
                                              const float* __restrict__ gt,
                                              const float* __restrict__ wc,
                                              const float* __restrict__ bc) {
  __shared__ float pl[64][64];
  int plane = blockIdx.x;
  int ch = plane & 255;
  int t = threadIdx.x;
  const float* src = out + (size_t)plane * HWHW;
#pragma unroll
  for (int ps = 0; ps < 4; ps++) {
    int i = ps * 1024 + t * 4;
    *(float4*)&pl[i >> 6][i & 63] = *(const float4*)(src + i);
  }
  float w[9];
#pragma unroll
  for (int i = 0; i < 9; i++) w[i] = wc[ch * 9 + i];
  float bias = bc[ch];
  __syncthreads();
#pragma unroll
  for (int ps = 0; ps < 16; ps++) {
    int pix = ps * 256 + t;
    int y = pix >> 6, x = pix & 63;
    float s = 0.0f;
#pragma unroll
    for (int dy = -1; dy <= 1; dy++) {
      int yy = y + dy;
      if (yy < 0 || yy > 63) continue;
#pragma unroll
      for (int dx = -1; dx <= 1; dx++) {
        int xx = x + dx;
        if (xx < 0 || xx > 63) continue;
        s += w[(dy + 1) * 3 + dx + 1] * pl[yy][xx];
      }
    }
    out[(size_t)plane * HWHW + pix] =
        (pl[y][x] + s + bias) * gt[(size_t)plane * HWHW + pix];
  }
}

extern "C" void kernel_launch(void* const* d_in, const int* in_sizes, int n_in,
                              void* d_out, int out_size, void* d_ws, size_t ws_size,
                              hipStream_t stream) {
  const float* x     = (const float*)d_in[0];
  const float* uw    = (const float*)d_in[1];
  const float* power = (const float*)d_in[2];
  const float* gw    = (const float*)d_in[3];
  const float* gb    = (const float*)d_in[4];
  const float* wc    = (const float*)d_in[5];
  const float* bcb   = (const float*)d_in[6];
  float* out   = (float*)d_out;
  float* score = out + (size_t)NN * CC;   // outputs concatenated: out, score
  float* ws = (float*)d_ws;

  float* xf    = ws + OFF_XF;
  float* gt    = ws + OFF_GT;
  float* rnorm = ws + OFF_RNORM;
  float* p     = ws + OFF_P;
  float* mn0   = ws + OFF_MN0;
  float* mnew  = ws + OFF_MNEW;
  float* sums  = ws + OFF_SUMS;
  float* cnts  = ws + OFF_COUNTS;
  float* kmean = ws + OFF_KMEAN;
  float* kvbig = ws + OFF_KVBIG;
  float* z     = ws + OFF_Z;
  float* z2    = ws + OFF_Z2;
  int*   ind   = (int*)(ws + OFF_IND);
  float* kkbuf = ws + OFF_KK;

  k_prep<<<1, 256, 0, stream>>>(power, p);
  k_zero<<<1542, 256, 0, stream>>>(sums);  // sums..kvbig contiguous
  k_transpose<<<dim3(128, 8, 8), dim3(32, 8), 0, stream>>>(x, xf);
  k_rownorm<<<8192, 256, 0, stream>>>(xf, rnorm);
  k_mnorm<<<256, 256, 0, stream>>>(uw, mn0);
  k_score<<<dim3(256, 8), 256, 0, stream>>>(xf, rnorm, mn0, score);
  k_g<<<dim3(256, 2), 256, 0, stream>>>(xf, gw, gb, gt);
  k_argmax<<<8192, 256, 0, stream>>>(score, ind);
  k_scatter<<<8192, 256, 0, stream>>>(xf, ind, sums, cnts);
  k_ema<<<256, 256, 0, stream>>>(uw, sums, cnts, p, mnew, kkbuf, kmean);
  k_kmean_fin<<<2, 256, 0, stream>>>(kmean);
  k_kv<<<dim3(8, 4, 8), 256, 0, stream>>>(kkbuf, mnew, kvbig);
  k_z<<<8192, 256, 0, stream>>>(xf, rnorm, p, kmean, z, z2);
  k_x<<<dim3(256, 2), 256, 0, stream>>>(xf, rnorm, p, kvbig, z, z2, out);
  k_conv<<<2048, 256, 0, stream>>>(out, gt, wc, bcb);
}

// Round 6
// 743.451 us; speedup vs baseline: 1.3018x; 1.3018x over previous
//
#include <hip/hip_runtime.h>
#include <math.h>

// Problem dims (fixed by setup_inputs)
#define BB 8
#define CC 256
#define HWHW 4096            // 64*64
#define NN 32768             // BB*HWHW
#define KD 1024
#define C2 512

// ---------------- workspace layout (float offsets) ----------------
#define OFF_XF     0u           // N*C  = 8388608   x in (n,c) layout
#define OFF_GT     8388608u     // N*C              g in (b,c,hw) layout
#define OFF_RNORM  16777216u    // N                1/||xf row||
#define OFF_P      16809984u    // C                p = 1+4*sigmoid(power)
#define OFF_MN0    16810240u    // K*C              l2norm(units_w)
#define OFF_MNEW   17072384u    // K*C              EMA-updated codebook
#define OFF_SUMS   17334528u    // K*C   (zeroed)
#define OFF_COUNTS 17596672u    // K     (zeroed)
#define OFF_KMEAN  17597696u    // 2C    (zeroed)
#define OFF_KVBIG  17598208u    // 256*512 (zeroed) kvT[c][t], fused [kv | shifted kv2]
#define OFF_Z      17729280u    // N
#define OFF_Z2     17762048u    // N
#define OFF_IND    17794816u    // N ints
#define OFF_KK     17827584u    // K*2C = 524288    power features of codebook
#define ZERO_CNT   394752u      // SUMS..KVBIG contiguous

typedef unsigned short u16;
typedef __attribute__((ext_vector_type(4))) unsigned short us4;
typedef __attribute__((ext_vector_type(8))) short s8;
typedef __attribute__((ext_vector_type(4))) float fx4;

__device__ __forceinline__ float wredsum(float v) {
#pragma unroll
  for (int o = 32; o; o >>= 1) v += __shfl_xor(v, o);
  return v;
}

// ---- bf16 hi/lo split helpers (RNE) ----
__device__ __forceinline__ u16 bf16h(float f) {
  unsigned u = __float_as_uint(f);
  return (u16)((u + 0x7FFFu + ((u >> 16) & 1u)) >> 16);
}
__device__ __forceinline__ void split1(float f, u16& h, u16& l) {
  u16 hh = bf16h(f);
  float hf = __uint_as_float(((unsigned)hh) << 16);
  h = hh;
  l = bf16h(f - hf);
}

// LDS fragment layout per matrix: [g(4)][row(128)][16B] where the 16B at
// (g,row) hold k = {g*4..g*4+3} (half 0) and {16+g*4..16+g*4+3} (half 1).
// Row offset swizzled by (row + 2g)&127 -> spread banks across g-groups.
// A k-chunk kc (4 consecutive k = kc*4..kc*4+3) maps to g=kc&3, half=kc>>2.
// NOTE: A and B staged identically => any k-permutation cancels in MFMA.
__device__ __forceinline__ void stage_pair(u16* __restrict__ H, u16* __restrict__ L,
                                           int kc, int row,
                                           float a0, float a1, float a2, float a3) {
  u16 h0, l0, h1, l1, h2, l2, h3, l3;
  split1(a0, h0, l0); split1(a1, h1, l1);
  split1(a2, h2, l2); split1(a3, h3, l3);
  int g = kc & 3;
  int off = g * 1024 + (((row + 2 * g) & 127) << 3) + ((kc >> 2) << 2);
  us4 hv = {h0, h1, h2, h3}, lv = {l0, l1, l2, l3};
  *(us4*)(H + off) = hv;
  *(us4*)(L + off) = lv;
}
__device__ __forceinline__ s8 fragld(const u16* __restrict__ M, int g, int r) {
  return *(const s8*)(M + g * 1024 + (((r + 2 * g) & 127) << 3));
}
#define MFMA(a, b, c) __builtin_amdgcn_mfma_f32_16x16x32_bf16((a), (b), (c), 0, 0, 0)

// p = 1 + 4*sigmoid(power)
__global__ void k_prep(const float* __restrict__ power, float* __restrict__ p) {
  int i = threadIdx.x;
  p[i] = 1.0f + 4.0f / (1.0f + expf(-power[i]));
}

__global__ void k_zero(float* __restrict__ zr) {
  unsigned i = blockIdx.x * 256u + threadIdx.x;
  if (i < ZERO_CNT) zr[i] = 0.0f;
}

// x (b,c,hw) -> xf (b*hw, c)
__global__ void k_transpose(const float* __restrict__ x, float* __restrict__ xf) {
  __shared__ float tile[32][33];
  int b = blockIdx.z, hw0 = blockIdx.x * 32, c0 = blockIdx.y * 32;
  int tx = threadIdx.x, ty = threadIdx.y;
#pragma unroll
  for (int i = 0; i < 32; i += 8)
    tile[ty + i][tx] = x[(size_t)(b * CC + c0 + ty + i) * HWHW + hw0 + tx];
  __syncthreads();
#pragma unroll
  for (int i = 0; i < 32; i += 8)
    xf[(size_t)(b * HWHW + hw0 + ty + i) * CC + c0 + tx] = tile[tx][ty + i];
}

// per-row 1/max(||row||, eps), one wave per row
__global__ void k_rownorm(const float* __restrict__ xf, float* __restrict__ rnorm) {
  int wv = threadIdx.x >> 6, ln = threadIdx.x & 63;
  int row = blockIdx.x * 4 + wv;
  float4 v = *(const float4*)(xf + (size_t)row * CC + ln * 4);
  float ss = wredsum(v.x * v.x + v.y * v.y + v.z * v.z + v.w * v.w);
  if (ln == 0) rnorm[row] = 1.0f / fmaxf(sqrtf(ss), 1e-12f);
}

// mn0 = l2norm(units_w) rows, one wave per row
__global__ void k_mnorm(const float* __restrict__ uw, float* __restrict__ mn0) {
  int wv = threadIdx.x >> 6, ln = threadIdx.x & 63;
  int row = blockIdx.x * 4 + wv;
  float4 v = *(const float4*)(uw + (size_t)row * CC + ln * 4);
  float ss = wredsum(v.x * v.x + v.y * v.y + v.z * v.z + v.w * v.w);
  float rn = 1.0f / fmaxf(sqrtf(ss), 1e-12f);
  float4 o = {v.x * rn, v.y * rn, v.z * rn, v.w * rn};
  *(float4*)(mn0 + (size_t)row * CC + ln * 4) = o;
}

// score = rn[n] * (xf @ mn0^T), split-bf16 MFMA, 128x128 tile, BK=32.
__global__ __launch_bounds__(256) void k_score_mfma(const float* __restrict__ xf,
                                                    const float* __restrict__ rnorm,
                                                    const float* __restrict__ mn0,
                                                    float* __restrict__ score) {
  __shared__ __align__(16) u16 Lds[4][4096];  // Ah, Al, Bh, Bl (8KB each)
  u16 *Ah = Lds[0], *Al = Lds[1], *Bh = Lds[2], *Bl = Lds[3];
  int t = threadIdx.x, w = t >> 6, l = t & 63;
  int wr = w >> 1, wc = w & 1;
  int kc = t & 7, lr = t >> 3;
  int row0 = blockIdx.x * 128, col0 = blockIdx.y * 128;
  fx4 acc[4][4];
#pragma unroll
  for (int i = 0; i < 4; i++)
#pragma unroll
    for (int j = 0; j < 4; j++) acc[i][j] = (fx4){0.f, 0.f, 0.f, 0.f};

  for (int k0 = 0; k0 < CC; k0 += 32) {
    __syncthreads();
#pragma unroll
    for (int ps = 0; ps < 4; ps++) {
      int row = lr + ps * 32;
      float4 va = *(const float4*)(xf + (size_t)(row0 + row) * CC + k0 + kc * 4);
      stage_pair(Ah, Al, kc, row, va.x, va.y, va.z, va.w);
      float4 vb = *(const float4*)(mn0 + (size_t)(col0 + row) * CC + k0 + kc * 4);
      stage_pair(Bh, Bl, kc, row, vb.x, vb.y, vb.z, vb.w);
    }
    __syncthreads();
    int g = l >> 4, rl = l & 15;
    s8 ah[4], al4[4], bh[4], bl4[4];
#pragma unroll
    for (int i = 0; i < 4; i++) {
      ah[i]  = fragld(Ah, g, wr * 64 + i * 16 + rl);
      al4[i] = fragld(Al, g, wr * 64 + i * 16 + rl);
      bh[i]  = fragld(Bh, g, wc * 64 + i * 16 + rl);
      bl4[i] = fragld(Bl, g, wc * 64 + i * 16 + rl);
    }
#pragma unroll
    for (int i = 0; i < 4; i++)
#pragma unroll
      for (int j = 0; j < 4; j++) {
        acc[i][j] = MFMA(ah[i], bh[j], acc[i][j]);
        acc[i][j] = MFMA(ah[i], bl4[j], acc[i][j]);
        acc[i][j] = MFMA(al4[i], bh[j], acc[i][j]);
      }
  }
  int row_l = (l >> 4) * 4, col_l = l & 15;
#pragma unroll
  for (int i = 0; i < 4; i++) {
    int rbase = row0 + wr * 64 + i * 16 + row_l;
    float4 rn4 = *(const float4*)(rnorm + rbase);
    float rr[4] = {rn4.x, rn4.y, rn4.z, rn4.w};
#pragma unroll
    for (int j = 0; j < 4; j++) {
      int col = col0 + wc * 64 + j * 16 + col_l;
#pragma unroll
      for (int reg = 0; reg < 4; reg++)
        score[(size_t)(rbase + reg) * KD + col] = acc[i][j][reg] * rr[reg];
    }
  }
}

// g = xf @ gw^T + gb, split-bf16 MFMA, stored transposed to (b,c,hw)
__global__ __launch_bounds__(256) void k_g_mfma(const float* __restrict__ xf,
                                                const float* __restrict__ gw,
                                                const float* __restrict__ gb,
                                                float* __restrict__ gt) {
  __shared__ __align__(16) u16 Lds[4][4096];
  u16 *Ah = Lds[0], *Al = Lds[1], *Bh = Lds[2], *Bl = Lds[3];
  int t = threadIdx.x, w = t >> 6, l = t & 63;
  int wr = w >> 1, wc = w & 1;
  int kc = t & 7, lr = t >> 3;
  int row0 = blockIdx.x * 128, col0 = blockIdx.y * 128;
  fx4 acc[4][4];
#pragma unroll
  for (int i = 0; i < 4; i++)
#pragma unroll
    for (int j = 0; j < 4; j++) acc[i][j] = (fx4){0.f, 0.f, 0.f, 0.f};

  for (int k0 = 0; k0 < CC; k0 += 32) {
    __syncthreads();
#pragma unroll
    for (int ps = 0; ps < 4; ps++) {
      int row = lr + ps * 32;
      float4 va = *(const float4*)(xf + (size_t)(row0 + row) * CC + k0 + kc * 4);
      stage_pair(Ah, Al, kc, row, va.x, va.y, va.z, va.w);
      float4 vb = *(const float4*)(gw + (size_t)(col0 + row) * CC + k0 + kc * 4);
      stage_pair(Bh, Bl, kc, row, vb.x, vb.y, vb.z, vb.w);
    }
    __syncthreads();
    int g = l >> 4, rl = l & 15;
    s8 ah[4], al4[4], bh[4], bl4[4];
#pragma unroll
    for (int i = 0; i < 4; i++) {
      ah[i]  = fragld(Ah, g, wr * 64 + i * 16 + rl);
      al4[i] = fragld(Al, g, wr * 64 + i * 16 + rl);
      bh[i]  = fragld(Bh, g, wc * 64 + i * 16 + rl);
      bl4[i] = fragld(Bl, g, wc * 64 + i * 16 + rl);
    }
#pragma unroll
    for (int i = 0; i < 4; i++)
#pragma unroll
      for (int j = 0; j < 4; j++) {
        acc[i][j] = MFMA(ah[i], bh[j], acc[i][j]);
        acc[i][j] = MFMA(ah[i], bl4[j], acc[i][j]);
        acc[i][j] = MFMA(al4[i], bh[j], acc[i][j]);
      }
  }
  int row_l = (l >> 4) * 4, col_l = l & 15;
#pragma unroll
  for (int j = 0; j < 4; j++) {
    int col = col0 + wc * 64 + j * 16 + col_l;
    float gbv = gb[col];
#pragma unroll
    for (int i = 0; i < 4; i++) {
      int rbase = row0 + wr * 64 + i * 16 + row_l;
#pragma unroll
      for (int reg = 0; reg < 4; reg++) {
        int row = rbase + reg;
        int b = row >> 12, hw = row & 4095;
        gt[(size_t)(b * CC + col) * HWHW + hw] = acc[i][j][reg] + gbv;
      }
    }
  }
}

// xo = (Q @ KVbig) * [z|z2]; Q (powf features) built inline in the loader;
// split-bf16 MFMA; stored transposed to (b,c,hw) directly in d_out.
__global__ __launch_bounds__(256) void k_x_mfma(const float* __restrict__ xf,
                                                const float* __restrict__ rnorm,
                                                const float* __restrict__ p,
                                                const float* __restrict__ kvT,
                                                const float* __restrict__ z,
                                                const float* __restrict__ z2,
                                                float* __restrict__ xot) {
  __shared__ __align__(16) u16 Lds[4][4096];
  u16 *Ah = Lds[0], *Al = Lds[1], *Bh = Lds[2], *Bl = Lds[3];
  int t = threadIdx.x, w = t >> 6, l = t & 63;
  int wr = w >> 1, wc = w & 1;
  int kc = t & 7, lr = t >> 3;
  int row0 = blockIdx.x * 128, col0 = blockIdx.y * 128;
  float rnA[4];
#pragma unroll
  for (int ps = 0; ps < 4; ps++) rnA[ps] = rnorm[row0 + lr + ps * 32];
  fx4 acc[4][4];
#pragma unroll
  for (int i = 0; i < 4; i++)
#pragma unroll
    for (int j = 0; j < 4; j++) acc[i][j] = (fx4){0.f, 0.f, 0.f, 0.f};

  for (int k0 = 0; k0 < C2; k0 += 32) {
    bool negh = (k0 >= 256);
    int c4 = (k0 & 255) + kc * 4;
    float4 p4 = *(const float4*)(p + c4);
    __syncthreads();
#pragma unroll
    for (int ps = 0; ps < 4; ps++) {
      int row = lr + ps * 32;
      float4 xv = *(const float4*)(xf + (size_t)(row0 + row) * CC + c4);
      float rn = rnA[ps];
      float b0 = negh ? -(xv.x * rn) : (xv.x * rn);
      float b1 = negh ? -(xv.y * rn) : (xv.y * rn);
      float b2 = negh ? -(xv.z * rn) : (xv.z * rn);
      float b3 = negh ? -(xv.w * rn) : (xv.w * rn);
      float q0 = b0 > 0.f ? powf(b0, p4.x) : 0.f;
      float q1 = b1 > 0.f ? powf(b1, p4.y) : 0.f;
      float q2 = b2 > 0.f ? powf(b2, p4.z) : 0.f;
      float q3 = b3 > 0.f ? powf(b3, p4.w) : 0.f;
      stage_pair(Ah, Al, kc, row, q0, q1, q2, q3);
      float4 vb = *(const float4*)(kvT + (size_t)(col0 + row) * C2 + k0 + kc * 4);
      stage_pair(Bh, Bl, kc, row, vb.x, vb.y, vb.z, vb.w);
    }
    __syncthreads();
    int g = l >> 4, rl = l & 15;
    s8 ah[4], al4[4], bh[4], bl4[4];
#pragma unroll
    for (int i = 0; i < 4; i++) {
      ah[i]  = fragld(Ah, g, wr * 64 + i * 16 + rl);
      al4[i] = fragld(Al, g, wr * 64 + i * 16 + rl);
      bh[i]  = fragld(Bh, g, wc * 64 + i * 16 + rl);
      bl4[i] = fragld(Bl, g, wc * 64 + i * 16 + rl);
    }
#pragma unroll
    for (int i = 0; i < 4; i++)
#pragma unroll
      for (int j = 0; j < 4; j++) {
        acc[i][j] = MFMA(ah[i], bh[j], acc[i][j]);
        acc[i][j] = MFMA(ah[i], bl4[j], acc[i][j]);
        acc[i][j] = MFMA(al4[i], bh[j], acc[i][j]);
      }
  }
  const float* zz = (col0 == 0) ? z : z2;
  int row_l = (l >> 4) * 4, col_l = l & 15;
#pragma unroll
  for (int i = 0; i < 4; i++) {
    int rbase = row0 + wr * 64 + i * 16 + row_l;
    float4 z4 = *(const float4*)(zz + rbase);
    float zr[4] = {z4.x, z4.y, z4.z, z4.w};
#pragma unroll
    for (int j = 0; j < 4; j++) {
      int col = col0 + wc * 64 + j * 16 + col_l;
#pragma unroll
      for (int reg = 0; reg < 4; reg++) {
        int row = rbase + reg;
        int b = row >> 12, hw = row & 4095;
        xot[(size_t)(b * CC + col) * HWHW + hw] = acc[i][j][reg] * zr[reg];
      }
    }
  }
}

// argmax over each score row (first max wins), one wave per row
__global__ void k_argmax(const float* __restrict__ score, int* __restrict__ ind) {
  int wv = threadIdx.x >> 6, ln = threadIdx.x & 63;
  int row = blockIdx.x * 4 + wv;
  const float* r = score + (size_t)row * KD;
  float best = -3.4e38f; int bi = 0;
#pragma unroll
  for (int ch = 0; ch < 4; ch++) {
    int base = ln * 16 + ch * 4;
    float4 v = *(const float4*)(r + base);
    float vv[4] = {v.x, v.y, v.z, v.w};
#pragma unroll
    for (int j = 0; j < 4; j++) {
      float val = vv[j]; int idx = base + j;
      if (val > best || (val == best && idx < bi)) { best = val; bi = idx; }
    }
  }
#pragma unroll
  for (int o = 32; o; o >>= 1) {
    float ov = __shfl_xor(best, o); int oi = __shfl_xor(bi, o);
    if (ov > best || (ov == best && oi < bi)) { best = ov; bi = oi; }
  }
  if (ln == 0) ind[row] = bi;
}

// scatter-add rows of xf into sums[ind], one wave per row
__global__ void k_scatter(const float* __restrict__ xf, const int* __restrict__ ind,
                          float* __restrict__ sums, float* __restrict__ counts) {
  int wv = threadIdx.x >> 6, ln = threadIdx.x & 63;
  int row = blockIdx.x * 4 + wv;
  int j = ind[row];
  const float* xr = xf + (size_t)row * CC;
  float* sb = sums + (size_t)j * CC;
#pragma unroll
  for (int c = 0; c < CC; c += 64) atomicAdd(&sb[c + ln], xr[c + ln]);
  if (ln == 0) atomicAdd(&counts[j], 1.0f);
}

// EMA update + normalized-power features kk + kmean accumulation. Wave per row.
__global__ void k_ema(const float* __restrict__ uw, const float* __restrict__ sums,
                      const float* __restrict__ counts, const float* __restrict__ p,
                      float* __restrict__ mnew, float* __restrict__ kkb,
                      float* __restrict__ kmean) {
  int wv = threadIdx.x >> 6, ln = threadIdx.x & 63;
  int j = blockIdx.x * 4 + wv;
  int c = ln * 4;
  float cnt = counts[j] + 1e-6f;
  float4 s4 = *(const float4*)(sums + (size_t)j * CC + c);
  float4 u4 = *(const float4*)(uw + (size_t)j * CC + c);
  float4 m4;
  m4.x = u4.x * 0.999f + (s4.x / cnt) * 0.001f;
  m4.y = u4.y * 0.999f + (s4.y / cnt) * 0.001f;
  m4.z = u4.z * 0.999f + (s4.z / cnt) * 0.001f;
  m4.w = u4.w * 0.999f + (s4.w / cnt) * 0.001f;
  *(float4*)(mnew + (size_t)j * CC + c) = m4;
  float ss = wredsum(m4.x * m4.x + m4.y * m4.y + m4.z * m4.z + m4.w * m4.w);
  float rn = 1.0f / fmaxf(sqrtf(ss), 1e-12f);
  float4 p4 = *(const float4*)(p + c);
  float mv[4] = {m4.x * rn, m4.y * rn, m4.z * rn, m4.w * rn};
  float pv[4] = {p4.x, p4.y, p4.z, p4.w};
  float kp[4], kn[4];
#pragma unroll
  for (int i = 0; i < 4; i++) {
    kp[i] = mv[i] > 0.0f ? powf(mv[i], pv[i]) : 0.0f;
    kn[i] = (-mv[i]) > 0.0f ? powf(-mv[i], pv[i]) : 0.0f;
  }
  float4 kp4 = {kp[0], kp[1], kp[2], kp[3]};
  float4 kn4 = {kn[0], kn[1], kn[2], kn[3]};
  *(float4*)(kkb + (size_t)j * C2 + c) = kp4;
  *(float4*)(kkb + (size_t)j * C2 + 256 + c) = kn4;
#pragma unroll
  for (int i = 0; i < 4; i++) {
    atomicAdd(&kmean[c + i], kp[i]);
    atomicAdd(&kmean[256 + c + i], kn[i]);
  }
}

__global__ void k_kmean_fin(float* __restrict__ kmean) {
  int i = blockIdx.x * 256 + threadIdx.x;
  if (i < C2) kmean[i] *= (1.0f / 1024.0f);
}

// kv_all = kk^T @ mnew / n, written TRANSPOSED into kvT[c][t] (256x512):
// kvT[c][t] = c<128 ? kv[t][c] : kv2[(t+256)&511][c-128]
__global__ __launch_bounds__(256) void k_kv(const float* __restrict__ kkb,
                                            const float* __restrict__ mnew,
                                            float* __restrict__ kvT) {
  __shared__ float Ks[32][64];
  __shared__ float Ms[32][64];
  int t = threadIdx.x;
  int t0 = blockIdx.x * 64, c0 = blockIdx.y * 64, kbase = blockIdx.z * 128;
  int cl4 = (t & 15) * 4, kr = t >> 4;
  int fr = (t & 15) * 4, fc = ((t >> 4) & 15) * 4;
  float acc[4][4] = {};
  for (int k0 = kbase; k0 < kbase + 128; k0 += 32) {
    __syncthreads();
#pragma unroll
    for (int ps = 0; ps < 2; ps++) {
      int kr2 = kr + ps * 16;
      *(float4*)&Ks[kr2][cl4] = *(const float4*)(kkb + (size_t)(k0 + kr2) * C2 + t0 + cl4);
      *(float4*)&Ms[kr2][cl4] = *(const float4*)(mnew + (size_t)(k0 + kr2) * CC + c0 + cl4);
    }
    __syncthreads();
#pragma unroll
    for (int kx = 0; kx < 32; kx++) {
      float4 a = *(const float4*)&Ks[kx][fr];
      float4 b = *(const float4*)&Ms[kx][fc];
      float av[4] = {a.x, a.y, a.z, a.w}, bv[4] = {b.x, b.y, b.z, b.w};
#pragma unroll
      for (int i = 0; i < 4; i++)
#pragma unroll
        for (int j = 0; j < 4; j++) acc[i][j] += av[i] * bv[j];
    }
  }
  const float sc = 1.0f / 32768.0f;
#pragma unroll
  for (int i = 0; i < 4; i++) {
    int tt = t0 + fr + i;
#pragma unroll
    for (int j = 0; j < 4; j++) {
      int c = c0 + fc + j;
      int drow = (c < 128) ? tt : ((tt + 256) & 511);
      atomicAdd(&kvT[(size_t)c * C2 + drow], acc[i][j] * sc);
    }
  }
}

// z = 1/(q_sim . kmean + eps), z2 = 1/(q_opp . kmean + eps). Wave per row.
__global__ void k_z(const float* __restrict__ xf, const float* __restrict__ rnorm,
                    const float* __restrict__ p, const float* __restrict__ kmean,
                    float* __restrict__ z, float* __restrict__ z2) {
  int wv = threadIdx.x >> 6, ln = threadIdx.x & 63;
  int row = blockIdx.x * 4 + wv;
  int c = ln * 4;
  float rn = rnorm[row];
  float4 v = *(const float4*)(xf + (size_t)row * CC + c);
  float4 p4 = *(const float4*)(p + c);
  float4 k0 = *(const float4*)(kmean + c);
  float4 k1 = *(const float4*)(kmean + 256 + c);
  float xv[4] = {v.x * rn, v.y * rn, v.z * rn, v.w * rn};
  float pv[4] = {p4.x, p4.y, p4.z, p4.w};
  float ka[4] = {k0.x, k0.y, k0.z, k0.w};
  float kb[4] = {k1.x, k1.y, k1.z, k1.w};
  float za = 0.0f, zb = 0.0f;
#pragma unroll
  for (int i = 0; i < 4; i++) {
    float qp = xv[i] > 0.0f ? powf(xv[i], pv[i]) : 0.0f;
    float qn = (-xv[i]) > 0.0f ? powf(-xv[i], pv[i]) : 0.0f;
    za += qp * ka[i] + qn * kb[i];
    zb += qn * ka[i] + qp * kb[i];
  }
  za = wredsum(za); zb = wredsum(zb);
  if (ln == 0) { z[row] = 1.0f / (za + 1e-6f); z2[row] = 1.0f / (zb + 1e-6f); }
}

// out = (xo + dwconv3x3(xo) + bias) * g, IN-PLACE on d_out per (b,ch) plane.
__global__ __launch_bounds__(256) void k_conv(float* __restrict__ out,
                                              const float* __restrict__ gt,
                                              const float* __restrict__ wc,
                                              const float* __restrict__ bc) {
  __shared__ float pl[64][64];
  int plane = blockIdx.x;
  int ch = plane & 255;
  int t = threadIdx.x;
  const float* src = out + (size_t)plane * HWHW;
#pragma unroll
  for (int ps = 0; ps < 4; ps++) {
    int i = ps * 1024 + t * 4;
    *(float4*)&pl[i >> 6][i & 63] = *(const float4*)(src + i);
  }
  float w[9];
#pragma unroll
  for (int i = 0; i < 9; i++) w[i] = wc[ch * 9 + i];
  float bias = bc[ch];
  __syncthreads();
#pragma unroll
  for (int ps = 0; ps < 16; ps++) {
    int pix = ps * 256 + t;
    int y = pix >> 6, x = pix & 63;
    float s = 0.0f;
#pragma unroll
    for (int dy = -1; dy <= 1; dy++) {
      int yy = y + dy;
      if (yy < 0 || yy > 63) continue;
#pragma unroll
      for (int dx = -1; dx <= 1; dx++) {
        int xx = x + dx;
        if (xx < 0 || xx > 63) continue;
        s += w[(dy + 1) * 3 + dx + 1] * pl[yy][xx];
      }
    }
    out[(size_t)plane * HWHW + pix] =
        (pl[y][x] + s + bias) * gt[(size_t)plane * HWHW + pix];
  }
}

extern "C" void kernel_launch(void* const* d_in, const int* in_sizes, int n_in,
                              void* d_out, int out_size, void* d_ws, size_t ws_size,
                              hipStream_t stream) {
  const float* x     = (const float*)d_in[0];
  const float* uw    = (const float*)d_in[1];
  const float* power = (const float*)d_in[2];
  const float* gw    = (const float*)d_in[3];
  const float* gb    = (const float*)d_in[4];
  const float* wc    = (const float*)d_in[5];
  const float* bcb   = (const float*)d_in[6];
  float* out   = (float*)d_out;
  float* score = out + (size_t)NN * CC;   // outputs concatenated: out, score
  float* ws = (float*)d_ws;

  float* xf    = ws + OFF_XF;
  float* gt    = ws + OFF_GT;
  float* rnorm = ws + OFF_RNORM;
  float* p     = ws + OFF_P;
  float* mn0   = ws + OFF_MN0;
  float* mnew  = ws + OFF_MNEW;
  float* sums  = ws + OFF_SUMS;
  float* cnts  = ws + OFF_COUNTS;
  float* kmean = ws + OFF_KMEAN;
  float* kvT   = ws + OFF_KVBIG;
  float* z     = ws + OFF_Z;
  float* z2    = ws + OFF_Z2;
  int*   ind   = (int*)(ws + OFF_IND);
  float* kkbuf = ws + OFF_KK;

  k_prep<<<1, 256, 0, stream>>>(power, p);
  k_zero<<<1542, 256, 0, stream>>>(sums);  // sums..kvT contiguous
  k_transpose<<<dim3(128, 8, 8), dim3(32, 8), 0, stream>>>(x, xf);
  k_rownorm<<<8192, 256, 0, stream>>>(xf, rnorm);
  k_mnorm<<<256, 256, 0, stream>>>(uw, mn0);
  k_score_mfma<<<dim3(256, 8), 256, 0, stream>>>(xf, rnorm, mn0, score);
  k_g_mfma<<<dim3(256, 2), 256, 0, stream>>>(xf, gw, gb, gt);
  k_argmax<<<8192, 256, 0, stream>>>(score, ind);
  k_scatter<<<8192, 256, 0, stream>>>(xf, ind, sums, cnts);
  k_ema<<<256, 256, 0, stream>>>(uw, sums, cnts, p, mnew, kkbuf, kmean);
  k_kmean_fin<<<2, 256, 0, stream>>>(kmean);
  k_kv<<<dim3(8, 4, 8), 256, 0, stream>>>(kkbuf, mnew, kvT);
  k_z<<<8192, 256, 0, stream>>>(xf, rnorm, p, kmean, z, z2);
  k_x_mfma<<<dim3(256, 2), 256, 0, stream>>>(xf, rnorm, p, kvT, z, z2, out);
  k_conv<<<2048, 256, 0, stream>>>(out, gt, wc, bcb);
}

// Round 7
// 546.887 us; speedup vs baseline: 1.7697x; 1.3594x over previous
//
#include <hip/hip_runtime.h>
#include <math.h>

// Problem dims (fixed by setup_inputs)
#define BB 8
#define CC 256
#define HWHW 4096            // 64*64
#define NN 32768             // BB*HWHW
#define KD 1024
#define C2 512

// ---------------- workspace layout (float offsets) ----------------
#define OFF_XF     0u           // N*C  = 8388608   x in (n,c) layout
#define OFF_GT     8388608u     // N*C              g in (b,c,hw) layout
#define OFF_RNORM  16777216u    // N                1/||xf row||
#define OFF_P      16809984u    // C                p = 1+4*sigmoid(power)
#define OFF_MN0    16810240u    // reused: MN0h (131072 f) + MN0l (131072 f) bf16 split of l2norm(units_w)
#define OFF_MNEW   17072384u    // K*C              EMA-updated codebook
#define OFF_SUMS   17334528u    // K*C   (zeroed)
#define OFF_COUNTS 17596672u    // K     (zeroed)
#define OFF_KMEAN  17597696u    // 2C    (zeroed)
#define OFF_KVBIG  17598208u    // 256*512 (zeroed) kvT[c][t] float, fused [kv | shifted kv2]
#define OFF_Z      17729280u    // N
#define OFF_Z2     17762048u    // N
#define OFF_IND    17794816u    // N ints
#define OFF_KK     17827584u    // K*2C = 524288    power features of codebook
#define OFF_GWS    18351872u    // GWh (32768 f) + GWl (32768 f)
#define OFF_KVS    18417408u    // KVTh (65536 f) + KVTl (65536 f)   end=18548480 (74.2MB)
#define ZERO_CNT   394752u      // SUMS..KVBIG contiguous

typedef unsigned short u16;
typedef __attribute__((ext_vector_type(4))) unsigned short us4;
typedef __attribute__((ext_vector_type(8))) short s8;
typedef __attribute__((ext_vector_type(4))) float fx4;

__device__ __forceinline__ float wredsum(float v) {
#pragma unroll
  for (int o = 32; o; o >>= 1) v += __shfl_xor(v, o);
  return v;
}

// ---- fast pow via HW transcendentals: b>0 required. exp2(p*log2(b)). ----
__device__ __forceinline__ float fpow(float b, float p) {
  return __builtin_amdgcn_exp2f(p * __builtin_amdgcn_logf(b));
}

// ---- bf16 hi/lo split helpers (RNE) ----
__device__ __forceinline__ u16 bf16h(float f) {
  unsigned u = __float_as_uint(f);
  return (u16)((u + 0x7FFFu + ((u >> 16) & 1u)) >> 16);
}
__device__ __forceinline__ void split1(float f, u16& h, u16& l) {
  u16 hh = bf16h(f);
  float hf = __uint_as_float(((unsigned)hh) << 16);
  h = hh;
  l = bf16h(f - hf);
}
__device__ __forceinline__ void split4(float a0, float a1, float a2, float a3,
                                       us4& hv, us4& lv) {
  u16 h0, l0, h1, l1, h2, l2, h3, l3;
  split1(a0, h0, l0); split1(a1, h1, l1);
  split1(a2, h2, l2); split1(a3, h3, l3);
  hv = (us4){h0, h1, h2, h3};
  lv = (us4){l0, l1, l2, l3};
}

// LDS fragment layout per matrix: [g(4)][row(128)][16B]; k-chunk kc -> g=kc&3,
// half=kc>>2; row offset swizzled by (row+2g)&127. A and B staged identically
// => k-permutation cancels in MFMA (only C/D layout must be exact).
__device__ __forceinline__ void stage_pre(u16* __restrict__ H, u16* __restrict__ L,
                                          int kc, int row, us4 hv, us4 lv) {
  int g = kc & 3;
  int off = g * 1024 + (((row + 2 * g) & 127) << 3) + ((kc >> 2) << 2);
  *(us4*)(H + off) = hv;
  *(us4*)(L + off) = lv;
}
__device__ __forceinline__ void stage_pair(u16* __restrict__ H, u16* __restrict__ L,
                                           int kc, int row,
                                           float a0, float a1, float a2, float a3) {
  us4 hv, lv;
  split4(a0, a1, a2, a3, hv, lv);
  stage_pre(H, L, kc, row, hv, lv);
}
__device__ __forceinline__ s8 fragld(const u16* __restrict__ M, int g, int r) {
  return *(const s8*)(M + g * 1024 + (((r + 2 * g) & 127) << 3));
}
#define MFMA(a, b, c) __builtin_amdgcn_mfma_f32_16x16x32_bf16((a), (b), (c), 0, 0, 0)

// p = 1 + 4*sigmoid(power)
__global__ void k_prep(const float* __restrict__ power, float* __restrict__ p) {
  int i = threadIdx.x;
  p[i] = 1.0f + 4.0f / (1.0f + expf(-power[i]));
}

__global__ void k_zero(float* __restrict__ zr) {
  unsigned i = blockIdx.x * 256u + threadIdx.x;
  if (i < ZERO_CNT) zr[i] = 0.0f;
}

// generic float -> bf16 hi/lo splitter, one float4 per thread
__global__ void k_splitbuf(const float* __restrict__ src, u16* __restrict__ h,
                           u16* __restrict__ l, int n4) {
  int i = blockIdx.x * 256 + threadIdx.x;
  if (i >= n4) return;
  float4 v = *(const float4*)(src + (size_t)i * 4);
  us4 hv, lv;
  split4(v.x, v.y, v.z, v.w, hv, lv);
  *(us4*)(h + (size_t)i * 4) = hv;
  *(us4*)(l + (size_t)i * 4) = lv;
}

// x (b,c,hw) -> xf (b*hw, c)
__global__ void k_transpose(const float* __restrict__ x, float* __restrict__ xf) {
  __shared__ float tile[32][33];
  int b = blockIdx.z, hw0 = blockIdx.x * 32, c0 = blockIdx.y * 32;
  int tx = threadIdx.x, ty = threadIdx.y;
#pragma unroll
  for (int i = 0; i < 32; i += 8)
    tile[ty + i][tx] = x[(size_t)(b * CC + c0 + ty + i) * HWHW + hw0 + tx];
  __syncthreads();
#pragma unroll
  for (int i = 0; i < 32; i += 8)
    xf[(size_t)(b * HWHW + hw0 + ty + i) * CC + c0 + tx] = tile[tx][ty + i];
}

// per-row 1/max(||row||, eps), one wave per row
__global__ void k_rownorm(const float* __restrict__ xf, float* __restrict__ rnorm) {
  int wv = threadIdx.x >> 6, ln = threadIdx.x & 63;
  int row = blockIdx.x * 4 + wv;
  float4 v = *(const float4*)(xf + (size_t)row * CC + ln * 4);
  float ss = wredsum(v.x * v.x + v.y * v.y + v.z * v.z + v.w * v.w);
  if (ln == 0) rnorm[row] = 1.0f / fmaxf(sqrtf(ss), 1e-12f);
}

// mn0 = l2norm(units_w), written directly as bf16 hi/lo. One wave per row.
__global__ void k_mnorm(const float* __restrict__ uw, u16* __restrict__ mh,
                        u16* __restrict__ ml) {
  int wv = threadIdx.x >> 6, ln = threadIdx.x & 63;
  int row = blockIdx.x * 4 + wv;
  float4 v = *(const float4*)(uw + (size_t)row * CC + ln * 4);
  float ss = wredsum(v.x * v.x + v.y * v.y + v.z * v.z + v.w * v.w);
  float rn = 1.0f / fmaxf(sqrtf(ss), 1e-12f);
  us4 hv, lv;
  split4(v.x * rn, v.y * rn, v.z * rn, v.w * rn, hv, lv);
  *(us4*)(mh + (size_t)row * CC + ln * 4) = hv;
  *(us4*)(ml + (size_t)row * CC + ln * 4) = lv;
}

// score = rn[n] * (xf @ mn0^T), split-bf16 MFMA, 128x128 tile, BK=32.
__global__ __launch_bounds__(256) void k_score_mfma(const float* __restrict__ xf,
                                                    const float* __restrict__ rnorm,
                                                    const u16* __restrict__ mh,
                                                    const u16* __restrict__ ml,
                                                    float* __restrict__ score) {
  __shared__ __align__(16) u16 Lds[4][4096];  // Ah, Al, Bh, Bl (8KB each)
  u16 *Ah = Lds[0], *Al = Lds[1], *Bh = Lds[2], *Bl = Lds[3];
  int t = threadIdx.x, w = t >> 6, l = t & 63;
  int wr = w >> 1, wc = w & 1;
  int kc = t & 7, lr = t >> 3;
  int row0 = blockIdx.x * 128, col0 = blockIdx.y * 128;
  fx4 acc[4][4];
#pragma unroll
  for (int i = 0; i < 4; i++)
#pragma unroll
    for (int j = 0; j < 4; j++) acc[i][j] = (fx4){0.f, 0.f, 0.f, 0.f};

  for (int k0 = 0; k0 < CC; k0 += 32) {
    __syncthreads();
#pragma unroll
    for (int ps = 0; ps < 4; ps++) {
      int row = lr + ps * 32;
      float4 va = *(const float4*)(xf + (size_t)(row0 + row) * CC + k0 + kc * 4);
      stage_pair(Ah, Al, kc, row, va.x, va.y, va.z, va.w);
      size_t bo = (size_t)(col0 + row) * CC + k0 + kc * 4;
      stage_pre(Bh, Bl, kc, row, *(const us4*)(mh + bo), *(const us4*)(ml + bo));
    }
    __syncthreads();
    int g = l >> 4, rl = l & 15;
    s8 ah[4], al4[4], bh[4], bl4[4];
#pragma unroll
    for (int i = 0; i < 4; i++) {
      ah[i]  = fragld(Ah, g, wr * 64 + i * 16 + rl);
      al4[i] = fragld(Al, g, wr * 64 + i * 16 + rl);
      bh[i]  = fragld(Bh, g, wc * 64 + i * 16 + rl);
      bl4[i] = fragld(Bl, g, wc * 64 + i * 16 + rl);
    }
#pragma unroll
    for (int i = 0; i < 4; i++)
#pragma unroll
      for (int j = 0; j < 4; j++) {
        acc[i][j] = MFMA(ah[i], bh[j], acc[i][j]);
        acc[i][j] = MFMA(ah[i], bl4[j], acc[i][j]);
        acc[i][j] = MFMA(al4[i], bh[j], acc[i][j]);
      }
  }
  int row_l = (l >> 4) * 4, col_l = l & 15;
#pragma unroll
  for (int i = 0; i < 4; i++) {
    int rbase = row0 + wr * 64 + i * 16 + row_l;
    float4 rn4 = *(const float4*)(rnorm + rbase);
    float rr[4] = {rn4.x, rn4.y, rn4.z, rn4.w};
#pragma unroll
    for (int j = 0; j < 4; j++) {
      int col = col0 + wc * 64 + j * 16 + col_l;
#pragma unroll
      for (int reg = 0; reg < 4; reg++)
        score[(size_t)(rbase + reg) * KD + col] = acc[i][j][reg] * rr[reg];
    }
  }
}

// g = xf @ gw^T + gb, split-bf16 MFMA (gw pre-split), stored to (b,c,hw)
__global__ __launch_bounds__(256) void k_g_mfma(const float* __restrict__ xf,
                                                const u16* __restrict__ gwh,
                                                const u16* __restrict__ gwl,
                                                const float* __restrict__ gb,
                                                float* __restrict__ gt) {
  __shared__ __align__(16) u16 Lds[4][4096];
  u16 *Ah = Lds[0], *Al = Lds[1], *Bh = Lds[2], *Bl = Lds[3];
  int t = threadIdx.x, w = t >> 6, l = t & 63;
  int wr = w >> 1, wc = w & 1;
  int kc = t & 7, lr = t >> 3;
  int row0 = blockIdx.x * 128, col0 = blockIdx.y * 128;
  fx4 acc[4][4];
#pragma unroll
  for (int i = 0; i < 4; i++)
#pragma unroll
    for (int j = 0; j < 4; j++) acc[i][j] = (fx4){0.f, 0.f, 0.f, 0.f};

  for (int k0 = 0; k0 < CC; k0 += 32) {
    __syncthreads();
#pragma unroll
    for (int ps = 0; ps < 4; ps++) {
      int row = lr + ps * 32;
      float4 va = *(const float4*)(xf + (size_t)(row0 + row) * CC + k0 + kc * 4);
      stage_pair(Ah, Al, kc, row, va.x, va.y, va.z, va.w);
      size_t bo = (size_t)(col0 + row) * CC + k0 + kc * 4;
      stage_pre(Bh, Bl, kc, row, *(const us4*)(gwh + bo), *(const us4*)(gwl + bo));
    }
    __syncthreads();
    int g = l >> 4, rl = l & 15;
    s8 ah[4], al4[4], bh[4], bl4[4];
#pragma unroll
    for (int i = 0; i < 4; i++) {
      ah[i]  = fragld(Ah, g, wr * 64 + i * 16 + rl);
      al4[i] = fragld(Al, g, wr * 64 + i * 16 + rl);
      bh[i]  = fragld(Bh, g, wc * 64 + i * 16 + rl);
      bl4[i] = fragld(Bl, g, wc * 64 + i * 16 + rl);
    }
#pragma unroll
    for (int i = 0; i < 4; i++)
#pragma unroll
      for (int j = 0; j < 4; j++) {
        acc[i][j] = MFMA(ah[i], bh[j], acc[i][j]);
        acc[i][j] = MFMA(ah[i], bl4[j], acc[i][j]);
        acc[i][j] = MFMA(al4[i], bh[j], acc[i][j]);
      }
  }
  int row_l = (l >> 4) * 4, col_l = l & 15;
#pragma unroll
  for (int j = 0; j < 4; j++) {
    int col = col0 + wc * 64 + j * 16 + col_l;
    float gbv = gb[col];
#pragma unroll
    for (int i = 0; i < 4; i++) {
      int rbase = row0 + wr * 64 + i * 16 + row_l;
#pragma unroll
      for (int reg = 0; reg < 4; reg++) {
        int row = rbase + reg;
        int b = row >> 12, hw = row & 4095;
        gt[(size_t)(b * CC + col) * HWHW + hw] = acc[i][j][reg] + gbv;
      }
    }
  }
}

// xo = (Q @ KVbig) * [z|z2]; Q via HW exp2/log2 in loader; kvT pre-split.
__global__ __launch_bounds__(256) void k_x_mfma(const float* __restrict__ xf,
                                                const float* __restrict__ rnorm,
                                                const float* __restrict__ p,
                                                const u16* __restrict__ kvh,
                                                const u16* __restrict__ kvl,
                                                const float* __restrict__ z,
                                                const float* __restrict__ z2,
                                                float* __restrict__ xot) {
  __shared__ __align__(16) u16 Lds[4][4096];
  u16 *Ah = Lds[0], *Al = Lds[1], *Bh = Lds[2], *Bl = Lds[3];
  int t = threadIdx.x, w = t >> 6, l = t & 63;
  int wr = w >> 1, wc = w & 1;
  int kc = t & 7, lr = t >> 3;
  int row0 = blockIdx.x * 128, col0 = blockIdx.y * 128;
  float rnA[4];
#pragma unroll
  for (int ps = 0; ps < 4; ps++) rnA[ps] = rnorm[row0 + lr + ps * 32];
  fx4 acc[4][4];
#pragma unroll
  for (int i = 0; i < 4; i++)
#pragma unroll
    for (int j = 0; j < 4; j++) acc[i][j] = (fx4){0.f, 0.f, 0.f, 0.f};

  for (int k0 = 0; k0 < C2; k0 += 32) {
    bool negh = (k0 >= 256);
    int c4 = (k0 & 255) + kc * 4;
    float4 p4 = *(const float4*)(p + c4);
    __syncthreads();
#pragma unroll
    for (int ps = 0; ps < 4; ps++) {
      int row = lr + ps * 32;
      float4 xv = *(const float4*)(xf + (size_t)(row0 + row) * CC + c4);
      float rn = rnA[ps];
      float b0 = negh ? -(xv.x * rn) : (xv.x * rn);
      float b1 = negh ? -(xv.y * rn) : (xv.y * rn);
      float b2 = negh ? -(xv.z * rn) : (xv.z * rn);
      float b3 = negh ? -(xv.w * rn) : (xv.w * rn);
      float q0 = b0 > 0.f ? fpow(b0, p4.x) : 0.f;
      float q1 = b1 > 0.f ? fpow(b1, p4.y) : 0.f;
      float q2 = b2 > 0.f ? fpow(b2, p4.z) : 0.f;
      float q3 = b3 > 0.f ? fpow(b3, p4.w) : 0.f;
      stage_pair(Ah, Al, kc, row, q0, q1, q2, q3);
      size_t bo = (size_t)(col0 + row) * C2 + k0 + kc * 4;
      stage_pre(Bh, Bl, kc, row, *(const us4*)(kvh + bo), *(const us4*)(kvl + bo));
    }
    __syncthreads();
    int g = l >> 4, rl = l & 15;
    s8 ah[4], al4[4], bh[4], bl4[4];
#pragma unroll
    for (int i = 0; i < 4; i++) {
      ah[i]  = fragld(Ah, g, wr * 64 + i * 16 + rl);
      al4[i] = fragld(Al, g, wr * 64 + i * 16 + rl);
      bh[i]  = fragld(Bh, g, wc * 64 + i * 16 + rl);
      bl4[i] = fragld(Bl, g, wc * 64 + i * 16 + rl);
    }
#pragma unroll
    for (int i = 0; i < 4; i++)
#pragma unroll
      for (int j = 0; j < 4; j++) {
        acc[i][j] = MFMA(ah[i], bh[j], acc[i][j]);
        acc[i][j] = MFMA(ah[i], bl4[j], acc[i][j]);
        acc[i][j] = MFMA(al4[i], bh[j], acc[i][j]);
      }
  }
  const float* zz = (col0 == 0) ? z : z2;
  int row_l = (l >> 4) * 4, col_l = l & 15;
#pragma unroll
  for (int i = 0; i < 4; i++) {
    int rbase = row0 + wr * 64 + i * 16 + row_l;
    float4 z4 = *(const float4*)(zz + rbase);
    float zr[4] = {z4.x, z4.y, z4.z, z4.w};
#pragma unroll
    for (int j = 0; j < 4; j++) {
      int col = col0 + wc * 64 + j * 16 + col_l;
#pragma unroll
      for (int reg = 0; reg < 4; reg++) {
        int row = rbase + reg;
        int b = row >> 12, hw = row & 4095;
        xot[(size_t)(b * CC + col) * HWHW + hw] = acc[i][j][reg] * zr[reg];
      }
    }
  }
}

// argmax over each score row (first max wins), one wave per row
__global__ void k_argmax(const float* __restrict__ score, int* __restrict__ ind) {
  int wv = threadIdx.x >> 6, ln = threadIdx.x & 63;
  int row = blockIdx.x * 4 + wv;
  const float* r = score + (size_t)row * KD;
  float best = -3.4e38f; int bi = 0;
#pragma unroll
  for (int ch = 0; ch < 4; ch++) {
    int base = ln * 16 + ch * 4;
    float4 v = *(const float4*)(r + base);
    float vv[4] = {v.x, v.y, v.z, v.w};
#pragma unroll
    for (int j = 0; j < 4; j++) {
      float val = vv[j]; int idx = base + j;
      if (val > best || (val == best && idx < bi)) { best = val; bi = idx; }
    }
  }
#pragma unroll
  for (int o = 32; o; o >>= 1) {
    float ov = __shfl_xor(best, o); int oi = __shfl_xor(bi, o);
    if (ov > best || (ov == best && oi < bi)) { best = ov; bi = oi; }
  }
  if (ln == 0) ind[row] = bi;
}

// scatter-add rows of xf into sums[ind], one wave per row
__global__ void k_scatter(const float* __restrict__ xf, const int* __restrict__ ind,
                          float* __restrict__ sums, float* __restrict__ counts) {
  int wv = threadIdx.x >> 6, ln = threadIdx.x & 63;
  int row = blockIdx.x * 4 + wv;
  int j = ind[row];
  const float* xr = xf + (size_t)row * CC;
  float* sb = sums + (size_t)j * CC;
#pragma unroll
  for (int c = 0; c < CC; c += 64) atomicAdd(&sb[c + ln], xr[c + ln]);
  if (ln == 0) atomicAdd(&counts[j], 1.0f);
}

// EMA update + normalized-power features kk + kmean accumulation. Wave per row.
__global__ void k_ema(const float* __restrict__ uw, const float* __restrict__ sums,
                      const float* __restrict__ counts, const float* __restrict__ p,
                      float* __restrict__ mnew, float* __restrict__ kkb,
                      float* __restrict__ kmean) {
  int wv = threadIdx.x >> 6, ln = threadIdx.x & 63;
  int j = blockIdx.x * 4 + wv;
  int c = ln * 4;
  float cnt = counts[j] + 1e-6f;
  float4 s4 = *(const float4*)(sums + (size_t)j * CC + c);
  float4 u4 = *(const float4*)(uw + (size_t)j * CC + c);
  float4 m4;
  m4.x = u4.x * 0.999f + (s4.x / cnt) * 0.001f;
  m4.y = u4.y * 0.999f + (s4.y / cnt) * 0.001f;
  m4.z = u4.z * 0.999f + (s4.z / cnt) * 0.001f;
  m4.w = u4.w * 0.999f + (s4.w / cnt) * 0.001f;
  *(float4*)(mnew + (size_t)j * CC + c) = m4;
  float ss = wredsum(m4.x * m4.x + m4.y * m4.y + m4.z * m4.z + m4.w * m4.w);
  float rn = 1.0f / fmaxf(sqrtf(ss), 1e-12f);
  float4 p4 = *(const float4*)(p + c);
  float mv[4] = {m4.x * rn, m4.y * rn, m4.z * rn, m4.w * rn};
  float pv[4] = {p4.x, p4.y, p4.z, p4.w};
  float kp[4], kn[4];
#pragma unroll
  for (int i = 0; i < 4; i++) {
    kp[i] = mv[i] > 0.0f ? fpow(mv[i], pv[i]) : 0.0f;
    kn[i] = (-mv[i]) > 0.0f ? fpow(-mv[i], pv[i]) : 0.0f;
  }
  float4 kp4 = {kp[0], kp[1], kp[2], kp[3]};
  float4 kn4 = {kn[0], kn[1], kn[2], kn[3]};
  *(float4*)(kkb + (size_t)j * C2 + c) = kp4;
  *(float4*)(kkb + (size_t)j * C2 + 256 + c) = kn4;
#pragma unroll
  for (int i = 0; i < 4; i++) {
    atomicAdd(&kmean[c + i], kp[i]);
    atomicAdd(&kmean[256 + c + i], kn[i]);
  }
}

__global__ void k_kmean_fin(float* __restrict__ kmean) {
  int i = blockIdx.x * 256 + threadIdx.x;
  if (i < C2) kmean[i] *= (1.0f / 1024.0f);
}

// kv_all = kk^T @ mnew / n, written TRANSPOSED into kvT[c][t] (256x512):
// kvT[c][t] = c<128 ? kv[t][c] : kv2[(t+256)&511][c-128]
__global__ __launch_bounds__(256) void k_kv(const float* __restrict__ kkb,
                                            const float* __restrict__ mnew,
                                            float* __restrict__ kvT) {
  __shared__ float Ks[32][64];
  __shared__ float Ms[32][64];
  int t = threadIdx.x;
  int t0 = blockIdx.x * 64, c0 = blockIdx.y * 64, kbase = blockIdx.z * 128;
  int cl4 = (t & 15) * 4, kr = t >> 4;
  int fr = (t & 15) * 4, fc = ((t >> 4) & 15) * 4;
  float acc[4][4] = {};
  for (int k0 = kbase; k0 < kbase + 128; k0 += 32) {
    __syncthreads();
#pragma unroll
    for (int ps = 0; ps < 2; ps++) {
      int kr2 = kr + ps * 16;
      *(float4*)&Ks[kr2][cl4] = *(const float4*)(kkb + (size_t)(k0 + kr2) * C2 + t0 + cl4);
      *(float4*)&Ms[kr2][cl4] = *(const float4*)(mnew + (size_t)(k0 + kr2) * CC + c0 + cl4);
    }
    __syncthreads();
#pragma unroll
    for (int kx = 0; kx < 32; kx++) {
      float4 a = *(const float4*)&Ks[kx][fr];
      float4 b = *(const float4*)&Ms[kx][fc];
      float av[4] = {a.x, a.y, a.z, a.w}, bv[4] = {b.x, b.y, b.z, b.w};
#pragma unroll
      for (int i = 0; i < 4; i++)
#pragma unroll
        for (int j = 0; j < 4; j++) acc[i][j] += av[i] * bv[j];
    }
  }
  const float sc = 1.0f / 32768.0f;
#pragma unroll
  for (int i = 0; i < 4; i++) {
    int tt = t0 + fr + i;
#pragma unroll
    for (int j = 0; j < 4; j++) {
      int c = c0 + fc + j;
      int drow = (c < 128) ? tt : ((tt + 256) & 511);
      atomicAdd(&kvT[(size_t)c * C2 + drow], acc[i][j] * sc);
    }
  }
}

// z = 1/(q_sim . kmean + eps), z2 = 1/(q_opp . kmean + eps). Wave per row.
__global__ void k_z(const float* __restrict__ xf, const float* __restrict__ rnorm,
                    const float* __restrict__ p, const float* __restrict__ kmean,
                    float* __restrict__ z, float* __restrict__ z2) {
  int wv = threadIdx.x >> 6, ln = threadIdx.x & 63;
  int row = blockIdx.x * 4 + wv;
  int c = ln * 4;
  float rn = rnorm[row];
  float4 v = *(const float4*)(xf + (size_t)row * CC + c);
  float4 p4 = *(const float4*)(p + c);
  float4 k0 = *(const float4*)(kmean + c);
  float4 k1 = *(const float4*)(kmean + 256 + c);
  float xv[4] = {v.x * rn, v.y * rn, v.z * rn, v.w * rn};
  float pv[4] = {p4.x, p4.y, p4.z, p4.w};
  float ka[4] = {k0.x, k0.y, k0.z, k0.w};
  float kb[4] = {k1.x, k1.y, k1.z, k1.w};
  float za = 0.0f, zb = 0.0f;
#pragma unroll
  for (int i = 0; i < 4; i++) {
    float qp = xv[i] > 0.0f ? fpow(xv[i], pv[i]) : 0.0f;
    float qn = (-xv[i]) > 0.0f ? fpow(-xv[i], pv[i]) : 0.0f;
    za += qp * ka[i] + qn * kb[i];
    zb += qn * ka[i] + qp * kb[i];
  }
  za = wredsum(za); zb = wredsum(zb);
  if (ln == 0) { z[row] = 1.0f / (za + 1e-6f); z2[row] = 1.0f / (zb + 1e-6f); }
}

// out = (xo + dwconv3x3(xo) + bias) * g, IN-PLACE on d_out per (b,ch) plane.
__global__ __launch_bounds__(256) void k_conv(float* __restrict__ out,
                                              const float* __restrict__ gt,
                                              const float* __restrict__ wc,
                                              const float* __restrict__ bc) {
  __shared__ float pl[64][64];
  int plane = blockIdx.x;
  int ch = plane & 255;
  int t = threadIdx.x;
  const float* src = out + (size_t)plane * HWHW;
#pragma unroll
  for (int ps = 0; ps < 4; ps++) {
    int i = ps * 1024 + t * 4;
    *(float4*)&pl[i >> 6][i & 63] = *(const float4*)(src + i);
  }
  float w[9];
#pragma unroll
  for (int i = 0; i < 9; i++) w[i] = wc[ch * 9 + i];
  float bias = bc[ch];
  __syncthreads();
#pragma unroll
  for (int ps = 0; ps < 16; ps++) {
    int pix = ps * 256 + t;
    int y = pix >> 6, x = pix & 63;
    float s = 0.0f;
#pragma unroll
    for (int dy = -1; dy <= 1; dy++) {
      int yy = y + dy;
      if (yy < 0 || yy > 63) continue;
#pragma unroll
      for (int dx = -1; dx <= 1; dx++) {
        int xx = x + dx;
        if (xx < 0 || xx > 63) continue;
        s += w[(dy + 1) * 3 + dx + 1] * pl[yy][xx];
      }
    }
    out[(size_t)plane * HWHW + pix] =
        (pl[y][x] + s + bias) * gt[(size_t)plane * HWHW + pix];
  }
}

extern "C" void kernel_launch(void* const* d_in, const int* in_sizes, int n_in,
                              void* d_out, int out_size, void* d_ws, size_t ws_size,
                              hipStream_t stream) {
  const float* x     = (const float*)d_in[0];
  const float* uw    = (const float*)d_in[1];
  const float* power = (const float*)d_in[2];
  const float* gw    = (const float*)d_in[3];
  const float* gb    = (const float*)d_in[4];
  const float* wc    = (const float*)d_in[5];
  const float* bcb   = (const float*)d_in[6];
  float* out   = (float*)d_out;
  float* score = out + (size_t)NN * CC;   // outputs concatenated: out, score
  float* ws = (float*)d_ws;

  float* xf    = ws + OFF_XF;
  float* gt    = ws + OFF_GT;
  float* rnorm = ws + OFF_RNORM;
  float* p     = ws + OFF_P;
  u16*   mn0h  = (u16*)(ws + OFF_MN0);
  u16*   mn0l  = (u16*)(ws + OFF_MN0 + 131072);
  float* mnew  = ws + OFF_MNEW;
  float* sums  = ws + OFF_SUMS;
  float* cnts  = ws + OFF_COUNTS;
  float* kmean = ws + OFF_KMEAN;
  float* kvT   = ws + OFF_KVBIG;
  float* z     = ws + OFF_Z;
  float* z2    = ws + OFF_Z2;
  int*   ind   = (int*)(ws + OFF_IND);
  float* kkbuf = ws + OFF_KK;
  u16*   gwh   = (u16*)(ws + OFF_GWS);
  u16*   gwl   = (u16*)(ws + OFF_GWS + 32768);
  u16*   kvh   = (u16*)(ws + OFF_KVS);
  u16*   kvl   = (u16*)(ws + OFF_KVS + 65536);

  k_prep<<<1, 256, 0, stream>>>(power, p);
  k_zero<<<1542, 256, 0, stream>>>(sums);  // sums..kvT contiguous
  k_transpose<<<dim3(128, 8, 8), dim3(32, 8), 0, stream>>>(x, xf);
  k_rownorm<<<8192, 256, 0, stream>>>(xf, rnorm);
  k_mnorm<<<256, 256, 0, stream>>>(uw, mn0h, mn0l);
  k_splitbuf<<<64, 256, 0, stream>>>(gw, gwh, gwl, 16384);       // gw 256x256
  k_score_mfma<<<dim3(256, 8), 256, 0, stream>>>(xf, rnorm, mn0h, mn0l, score);
  k_g_mfma<<<dim3(256, 2), 256, 0, stream>>>(xf, gwh, gwl, gb, gt);
  k_argmax<<<8192, 256, 0, stream>>>(score, ind);
  k_scatter<<<8192, 256, 0, stream>>>(xf, ind, sums, cnts);
  k_ema<<<256, 256, 0, stream>>>(uw, sums, cnts, p, mnew, kkbuf, kmean);
  k_kmean_fin<<<2, 256, 0, stream>>>(kmean);
  k_kv<<<dim3(8, 4, 8), 256, 0, stream>>>(kkbuf, mnew, kvT);
  k_splitbuf<<<128, 256, 0, stream>>>(kvT, kvh, kvl, 32768);     // kvT 256x512
  k_z<<<8192, 256, 0, stream>>>(xf, rnorm, p, kmean, z, z2);
  k_x_mfma<<<dim3(256, 2), 256, 0, stream>>>(xf, rnorm, p, kvh, kvl, z, z2, out);
  k_conv<<<2048, 256, 0, stream>>>(out, gt, wc, bcb);
}

// Round 9
// 459.180 us; speedup vs baseline: 2.1078x; 1.1910x over previous
//
#include <hip/hip_runtime.h>
#include <math.h>

// Problem dims (fixed by setup_inputs)
#define BB 8
#define CC 256
#define HWHW 4096            // 64*64
#define NN 32768             // BB*HWHW
#define KD 1024
#define C2 512

// ---------------- workspace layout (float offsets) ----------------
#define OFF_XF     0u           // N*C  = 8388608   x in (n,c) layout
#define OFF_GT     8388608u     // N*C              g in (b,c,hw) layout
#define OFF_RNORM  16777216u    // N                1/||xf row||
#define OFF_P      16809984u    // C                p = 1+4*sigmoid(power)
#define OFF_MN0    16810240u    // MN0h (131072 f) + MN0l (131072 f) bf16 split of l2norm(units_w)
#define OFF_MNEW   17072384u    // K*C              EMA-updated codebook
#define OFF_SUMS   17334528u    // K*C   (zeroed)
#define OFF_COUNTS 17596672u    // K     (zeroed)
#define OFF_KMEAN  17597696u    // 2C
#define OFF_KVBIG  17598208u    // 256*512 (zeroed) kvT[c][t] float, fused [kv | shifted kv2]
#define OFF_Z      17729280u    // N
#define OFF_Z2     17762048u    // N
#define OFF_IND    17794816u    // N ints
#define OFF_KK     17827584u    // K*2C = 524288    power features of codebook
#define OFF_GWS    18351872u    // GWh (32768 f) + GWl (32768 f)
#define OFF_KVS    18417408u    // KVTh (65536 f) + KVTl (65536 f)   end=18548480 (74.2MB)
#define ZERO_CNT   394752u      // SUMS..KVBIG contiguous

typedef unsigned short u16;
typedef __attribute__((ext_vector_type(4))) unsigned short us4;
typedef __attribute__((ext_vector_type(8))) short s8;
typedef __attribute__((ext_vector_type(4))) float fx4;

__device__ __forceinline__ float wredsum(float v) {
#pragma unroll
  for (int o = 32; o; o >>= 1) v += __shfl_xor(v, o);
  return v;
}

// ---- fast pow via HW transcendentals: b>0 required. exp2(p*log2(b)). ----
__device__ __forceinline__ float fpow(float b, float p) {
  return __builtin_amdgcn_exp2f(p * __builtin_amdgcn_logf(b));
}

// ---- bf16 hi/lo split helpers (RNE) ----
__device__ __forceinline__ u16 bf16h(float f) {
  unsigned u = __float_as_uint(f);
  return (u16)((u + 0x7FFFu + ((u >> 16) & 1u)) >> 16);
}
__device__ __forceinline__ void split1(float f, u16& h, u16& l) {
  u16 hh = bf16h(f);
  float hf = __uint_as_float(((unsigned)hh) << 16);
  h = hh;
  l = bf16h(f - hf);
}
__device__ __forceinline__ void split4(float a0, float a1, float a2, float a3,
                                       us4& hv, us4& lv) {
  u16 h0, l0, h1, l1, h2, l2, h3, l3;
  split1(a0, h0, l0); split1(a1, h1, l1);
  split1(a2, h2, l2); split1(a3, h3, l3);
  hv = (us4){h0, h1, h2, h3};
  lv = (us4){l0, l1, l2, l3};
}

// LDS fragment layout per matrix: [g(4)][row(128)][16B]; k-chunk kc -> g=kc&3,
// half=kc>>2; row offset swizzled by (row+2g)&127. A and B staged identically
// => k-permutation cancels in MFMA (only C/D layout must be exact).
__device__ __forceinline__ void stage_pre(u16* __restrict__ H, u16* __restrict__ L,
                                          int kc, int row, us4 hv, us4 lv) {
  int g = kc & 3;
  int off = g * 1024 + (((row + 2 * g) & 127) << 3) + ((kc >> 2) << 2);
  *(us4*)(H + off) = hv;
  *(us4*)(L + off) = lv;
}
__device__ __forceinline__ void stage_pair(u16* __restrict__ H, u16* __restrict__ L,
                                           int kc, int row,
                                           float a0, float a1, float a2, float a3) {
  us4 hv, lv;
  split4(a0, a1, a2, a3, hv, lv);
  stage_pre(H, L, kc, row, hv, lv);
}
__device__ __forceinline__ s8 fragld(const u16* __restrict__ M, int g, int r) {
  return *(const s8*)(M + g * 1024 + (((r + 2 * g) & 127) << 3));
}
#define MFMA(a, b, c) __builtin_amdgcn_mfma_f32_16x16x32_bf16((a), (b), (c), 0, 0, 0)

// p = 1 + 4*sigmoid(power)
__global__ void k_prep(const float* __restrict__ power, float* __restrict__ p) {
  int i = threadIdx.x;
  p[i] = 1.0f + 4.0f / (1.0f + expf(-power[i]));
}

__global__ void k_zero(float* __restrict__ zr) {
  unsigned i = blockIdx.x * 256u + threadIdx.x;
  if (i < ZERO_CNT) zr[i] = 0.0f;
}

// generic float -> bf16 hi/lo splitter, one float4 per thread
__global__ void k_splitbuf(const float* __restrict__ src, u16* __restrict__ h,
                           u16* __restrict__ l, int n4) {
  int i = blockIdx.x * 256 + threadIdx.x;
  if (i >= n4) return;
  float4 v = *(const float4*)(src + (size_t)i * 4);
  us4 hv, lv;
  split4(v.x, v.y, v.z, v.w, hv, lv);
  *(us4*)(h + (size_t)i * 4) = hv;
  *(us4*)(l + (size_t)i * 4) = lv;
}

// x (b,c,hw) -> xf (b*hw, c)
__global__ void k_transpose(const float* __restrict__ x, float* __restrict__ xf) {
  __shared__ float tile[32][33];
  int b = blockIdx.z, hw0 = blockIdx.x * 32, c0 = blockIdx.y * 32;
  int tx = threadIdx.x, ty = threadIdx.y;
#pragma unroll
  for (int i = 0; i < 32; i += 8)
    tile[ty + i][tx] = x[(size_t)(b * CC + c0 + ty + i) * HWHW + hw0 + tx];
  __syncthreads();
#pragma unroll
  for (int i = 0; i < 32; i += 8)
    xf[(size_t)(b * HWHW + hw0 + ty + i) * CC + c0 + tx] = tile[tx][ty + i];
}

// per-row 1/max(||row||, eps), one wave per row
__global__ void k_rownorm(const float* __restrict__ xf, float* __restrict__ rnorm) {
  int wv = threadIdx.x >> 6, ln = threadIdx.x & 63;
  int row = blockIdx.x * 4 + wv;
  float4 v = *(const float4*)(xf + (size_t)row * CC + ln * 4);
  float ss = wredsum(v.x * v.x + v.y * v.y + v.z * v.z + v.w * v.w);
  if (ln == 0) rnorm[row] = 1.0f / fmaxf(sqrtf(ss), 1e-12f);
}

// mn0 = l2norm(units_w), written directly as bf16 hi/lo. One wave per row.
__global__ void k_mnorm(const float* __restrict__ uw, u16* __restrict__ mh,
                        u16* __restrict__ ml) {
  int wv = threadIdx.x >> 6, ln = threadIdx.x & 63;
  int row = blockIdx.x * 4 + wv;
  float4 v = *(const float4*)(uw + (size_t)row * CC + ln * 4);
  float ss = wredsum(v.x * v.x + v.y * v.y + v.z * v.z + v.w * v.w);
  float rn = 1.0f / fmaxf(sqrtf(ss), 1e-12f);
  us4 hv, lv;
  split4(v.x * rn, v.y * rn, v.z * rn, v.w * rn, hv, lv);
  *(us4*)(mh + (size_t)row * CC + ln * 4) = hv;
  *(us4*)(ml + (size_t)row * CC + ln * 4) = lv;
}

// score = rn[n] * (xf @ mn0^T), split-bf16 MFMA, 128x128 tile, BK=32.
__global__ __launch_bounds__(256) void k_score_mfma(const float* __restrict__ xf,
                                                    const float* __restrict__ rnorm,
                                                    const u16* __restrict__ mh,
                                                    const u16* __restrict__ ml,
                                                    float* __restrict__ score) {
  __shared__ __align__(16) u16 Lds[4][4096];  // Ah, Al, Bh, Bl (8KB each)
  u16 *Ah = Lds[0], *Al = Lds[1], *Bh = Lds[2], *Bl = Lds[3];
  int t = threadIdx.x, w = t >> 6, l = t & 63;
  int wr = w >> 1, wc = w & 1;
  int kc = t & 7, lr = t >> 3;
  int row0 = blockIdx.x * 128, col0 = blockIdx.y * 128;
  fx4 acc[4][4];
#pragma unroll
  for (int i = 0; i < 4; i++)
#pragma unroll
    for (int j = 0; j < 4; j++) acc[i][j] = (fx4){0.f, 0.f, 0.f, 0.f};

  for (int k0 = 0; k0 < CC; k0 += 32) {
    __syncthreads();
#pragma unroll
    for (int ps = 0; ps < 4; ps++) {
      int row = lr + ps * 32;
      float4 va = *(const float4*)(xf + (size_t)(row0 + row) * CC + k0 + kc * 4);
      stage_pair(Ah, Al, kc, row, va.x, va.y, va.z, va.w);
      size_t bo = (size_t)(col0 + row) * CC + k0 + kc * 4;
      stage_pre(Bh, Bl, kc, row, *(const us4*)(mh + bo), *(const us4*)(ml + bo));
    }
    __syncthreads();
    int g = l >> 4, rl = l & 15;
    s8 ah[4], al4[4], bh[4], bl4[4];
#pragma unroll
    for (int i = 0; i < 4; i++) {
      ah[i]  = fragld(Ah, g, wr * 64 + i * 16 + rl);
      al4[i] = fragld(Al, g, wr * 64 + i * 16 + rl);
      bh[i]  = fragld(Bh, g, wc * 64 + i * 16 + rl);
      bl4[i] = fragld(Bl, g, wc * 64 + i * 16 + rl);
    }
#pragma unroll
    for (int i = 0; i < 4; i++)
#pragma unroll
      for (int j = 0; j < 4; j++) {
        acc[i][j] = MFMA(ah[i], bh[j], acc[i][j]);
        acc[i][j] = MFMA(ah[i], bl4[j], acc[i][j]);
        acc[i][j] = MFMA(al4[i], bh[j], acc[i][j]);
      }
  }
  int row_l = (l >> 4) * 4, col_l = l & 15;
#pragma unroll
  for (int i = 0; i < 4; i++) {
    int rbase = row0 + wr * 64 + i * 16 + row_l;
    float4 rn4 = *(const float4*)(rnorm + rbase);
    float rr[4] = {rn4.x, rn4.y, rn4.z, rn4.w};
#pragma unroll
    for (int j = 0; j < 4; j++) {
      int col = col0 + wc * 64 + j * 16 + col_l;
#pragma unroll
      for (int reg = 0; reg < 4; reg++)
        score[(size_t)(rbase + reg) * KD + col] = acc[i][j][reg] * rr[reg];
    }
  }
}

// g = xf @ gw^T + gb, split-bf16 MFMA (gw pre-split), stored to (b,c,hw)
__global__ __launch_bounds__(256) void k_g_mfma(const float* __restrict__ xf,
                                                const u16* __restrict__ gwh,
                                                const u16* __restrict__ gwl,
                                                const float* __restrict__ gb,
                                                float* __restrict__ gt) {
  __shared__ __align__(16) u16 Lds[4][4096];
  u16 *Ah = Lds[0], *Al = Lds[1], *Bh = Lds[2], *Bl = Lds[3];
  int t = threadIdx.x, w = t >> 6, l = t & 63;
  int wr = w >> 1, wc = w & 1;
  int kc = t & 7, lr = t >> 3;
  int row0 = blockIdx.x * 128, col0 = blockIdx.y * 128;
  fx4 acc[4][4];
#pragma unroll
  for (int i = 0; i < 4; i++)
#pragma unroll
    for (int j = 0; j < 4; j++) acc[i][j] = (fx4){0.f, 0.f, 0.f, 0.f};

  for (int k0 = 0; k0 < CC; k0 += 32) {
    __syncthreads();
#pragma unroll
    for (int ps = 0; ps < 4; ps++) {
      int row = lr + ps * 32;
      float4 va = *(const float4*)(xf + (size_t)(row0 + row) * CC + k0 + kc * 4);
      stage_pair(Ah, Al, kc, row, va.x, va.y, va.z, va.w);
      size_t bo = (size_t)(col0 + row) * CC + k0 + kc * 4;
      stage_pre(Bh, Bl, kc, row, *(const us4*)(gwh + bo), *(const us4*)(gwl + bo));
    }
    __syncthreads();
    int g = l >> 4, rl = l & 15;
    s8 ah[4], al4[4], bh[4], bl4[4];
#pragma unroll
    for (int i = 0; i < 4; i++) {
      ah[i]  = fragld(Ah, g, wr * 64 + i * 16 + rl);
      al4[i] = fragld(Al, g, wr * 64 + i * 16 + rl);
      bh[i]  = fragld(Bh, g, wc * 64 + i * 16 + rl);
      bl4[i] = fragld(Bl, g, wc * 64 + i * 16 + rl);
    }
#pragma unroll
    for (int i = 0; i < 4; i++)
#pragma unroll
      for (int j = 0; j < 4; j++) {
        acc[i][j] = MFMA(ah[i], bh[j], acc[i][j]);
        acc[i][j] = MFMA(ah[i], bl4[j], acc[i][j]);
        acc[i][j] = MFMA(al4[i], bh[j], acc[i][j]);
      }
  }
  int row_l = (l >> 4) * 4, col_l = l & 15;
#pragma unroll
  for (int j = 0; j < 4; j++) {
    int col = col0 + wc * 64 + j * 16 + col_l;
    float gbv = gb[col];
#pragma unroll
    for (int i = 0; i < 4; i++) {
      int rbase = row0 + wr * 64 + i * 16 + row_l;
#pragma unroll
      for (int reg = 0; reg < 4; reg++) {
        int row = rbase + reg;
        int b = row >> 12, hw = row & 4095;
        gt[(size_t)(b * CC + col) * HWHW + hw] = acc[i][j][reg] + gbv;
      }
    }
  }
}

// xo = (Q @ KVbig) * [z|z2]; Q via HW exp2/log2 in loader; kvT pre-split.
__global__ __launch_bounds__(256) void k_x_mfma(const float* __restrict__ xf,
                                                const float* __restrict__ rnorm,
                                                const float* __restrict__ p,
                                                const u16* __restrict__ kvh,
                                                const u16* __restrict__ kvl,
                                                const float* __restrict__ z,
                                                const float* __restrict__ z2,
                                                float* __restrict__ xot) {
  __shared__ __align__(16) u16 Lds[4][4096];
  u16 *Ah = Lds[0], *Al = Lds[1], *Bh = Lds[2], *Bl = Lds[3];
  int t = threadIdx.x, w = t >> 6, l = t & 63;
  int wr = w >> 1, wc = w & 1;
  int kc = t & 7, lr = t >> 3;
  int row0 = blockIdx.x * 128, col0 = blockIdx.y * 128;
  float rnA[4];
#pragma unroll
  for (int ps = 0; ps < 4; ps++) rnA[ps] = rnorm[row0 + lr + ps * 32];
  fx4 acc[4][4];
#pragma unroll
  for (int i = 0; i < 4; i++)
#pragma unroll
    for (int j = 0; j < 4; j++) acc[i][j] = (fx4){0.f, 0.f, 0.f, 0.f};

  for (int k0 = 0; k0 < C2; k0 += 32) {
    bool negh = (k0 >= 256);
    int c4 = (k0 & 255) + kc * 4;
    float4 p4 = *(const float4*)(p + c4);
    __syncthreads();
#pragma unroll
    for (int ps = 0; ps < 4; ps++) {
      int row = lr + ps * 32;
      float4 xv = *(const float4*)(xf + (size_t)(row0 + row) * CC + c4);
      float rn = rnA[ps];
      float b0 = negh ? -(xv.x * rn) : (xv.x * rn);
      float b1 = negh ? -(xv.y * rn) : (xv.y * rn);
      float b2 = negh ? -(xv.z * rn) : (xv.z * rn);
      float b3 = negh ? -(xv.w * rn) : (xv.w * rn);
      float q0 = b0 > 0.f ? fpow(b0, p4.x) : 0.f;
      float q1 = b1 > 0.f ? fpow(b1, p4.y) : 0.f;
      float q2 = b2 > 0.f ? fpow(b2, p4.z) : 0.f;
      float q3 = b3 > 0.f ? fpow(b3, p4.w) : 0.f;
      stage_pair(Ah, Al, kc, row, q0, q1, q2, q3);
      size_t bo = (size_t)(col0 + row) * C2 + k0 + kc * 4;
      stage_pre(Bh, Bl, kc, row, *(const us4*)(kvh + bo), *(const us4*)(kvl + bo));
    }
    __syncthreads();
    int g = l >> 4, rl = l & 15;
    s8 ah[4], al4[4], bh[4], bl4[4];
#pragma unroll
    for (int i = 0; i < 4; i++) {
      ah[i]  = fragld(Ah, g, wr * 64 + i * 16 + rl);
      al4[i] = fragld(Al, g, wr * 64 + i * 16 + rl);
      bh[i]  = fragld(Bh, g, wc * 64 + i * 16 + rl);
      bl4[i] = fragld(Bl, g, wc * 64 + i * 16 + rl);
    }
#pragma unroll
    for (int i = 0; i < 4; i++)
#pragma unroll
      for (int j = 0; j < 4; j++) {
        acc[i][j] = MFMA(ah[i], bh[j], acc[i][j]);
        acc[i][j] = MFMA(ah[i], bl4[j], acc[i][j]);
        acc[i][j] = MFMA(al4[i], bh[j], acc[i][j]);
      }
  }
  const float* zz = (col0 == 0) ? z : z2;
  int row_l = (l >> 4) * 4, col_l = l & 15;
#pragma unroll
  for (int i = 0; i < 4; i++) {
    int rbase = row0 + wr * 64 + i * 16 + row_l;
    float4 z4 = *(const float4*)(zz + rbase);
    float zr[4] = {z4.x, z4.y, z4.z, z4.w};
#pragma unroll
    for (int j = 0; j < 4; j++) {
      int col = col0 + wc * 64 + j * 16 + col_l;
#pragma unroll
      for (int reg = 0; reg < 4; reg++) {
        int row = rbase + reg;
        int b = row >> 12, hw = row & 4095;
        xot[(size_t)(b * CC + col) * HWHW + hw] = acc[i][j][reg] * zr[reg];
      }
    }
  }
}

// argmax over each score row (first max wins), one wave per row
__global__ void k_argmax(const float* __restrict__ score, int* __restrict__ ind) {
  int wv = threadIdx.x >> 6, ln = threadIdx.x & 63;
  int row = blockIdx.x * 4 + wv;
  const float* r = score + (size_t)row * KD;
  float best = -3.4e38f; int bi = 0;
#pragma unroll
  for (int ch = 0; ch < 4; ch++) {
    int base = ln * 16 + ch * 4;
    float4 v = *(const float4*)(r + base);
    float vv[4] = {v.x, v.y, v.z, v.w};
#pragma unroll
    for (int j = 0; j < 4; j++) {
      float val = vv[j]; int idx = base + j;
      if (val > best || (val == best && idx < bi)) { best = val; bi = idx; }
    }
  }
#pragma unroll
  for (int o = 32; o; o >>= 1) {
    float ov = __shfl_xor(best, o); int oi = __shfl_xor(bi, o);
    if (ov > best || (ov == best && oi < bi)) { best = ov; bi = oi; }
  }
  if (ln == 0) ind[row] = bi;
}

// scatter-add rows of xf into sums[ind], one wave per row
__global__ void k_scatter(const float* __restrict__ xf, const int* __restrict__ ind,
                          float* __restrict__ sums, float* __restrict__ counts) {
  int wv = threadIdx.x >> 6, ln = threadIdx.x & 63;
  int row = blockIdx.x * 4 + wv;
  int j = ind[row];
  const float* xr = xf + (size_t)row * CC;
  float* sb = sums + (size_t)j * CC;
#pragma unroll
  for (int c = 0; c < CC; c += 64) atomicAdd(&sb[c + ln], xr[c + ln]);
  if (ln == 0) atomicAdd(&counts[j], 1.0f);
}

// EMA update + normalized-power features kk. Wave per row. (kmean atomics
// removed -> separate k_kmean reduction; was 1024-way contention = 101 us.)
__global__ void k_ema(const float* __restrict__ uw, const float* __restrict__ sums,
                      const float* __restrict__ counts, const float* __restrict__ p,
                      float* __restrict__ mnew, float* __restrict__ kkb) {
  int wv = threadIdx.x >> 6, ln = threadIdx.x & 63;
  int j = blockIdx.x * 4 + wv;
  int c = ln * 4;
  float cnt = counts[j] + 1e-6f;
  float4 s4 = *(const float4*)(sums + (size_t)j * CC + c);
  float4 u4 = *(const float4*)(uw + (size_t)j * CC + c);
  float4 m4;
  m4.x = u4.x * 0.999f + (s4.x / cnt) * 0.001f;
  m4.y = u4.y * 0.999f + (s4.y / cnt) * 0.001f;
  m4.z = u4.z * 0.999f + (s4.z / cnt) * 0.001f;
  m4.w = u4.w * 0.999f + (s4.w / cnt) * 0.001f;
  *(float4*)(mnew + (size_t)j * CC + c) = m4;
  float ss = wredsum(m4.x * m4.x + m4.y * m4.y + m4.z * m4.z + m4.w * m4.w);
  float rn = 1.0f / fmaxf(sqrtf(ss), 1e-12f);
  float4 p4 = *(const float4*)(p + c);
  float mv[4] = {m4.x * rn, m4.y * rn, m4.z * rn, m4.w * rn};
  float pv[4] = {p4.x, p4.y, p4.z, p4.w};
  float kp[4], kn[4];
#pragma unroll
  for (int i = 0; i < 4; i++) {
    kp[i] = mv[i] > 0.0f ? fpow(mv[i], pv[i]) : 0.0f;
    kn[i] = (-mv[i]) > 0.0f ? fpow(-mv[i], pv[i]) : 0.0f;
  }
  float4 kp4 = {kp[0], kp[1], kp[2], kp[3]};
  float4 kn4 = {kn[0], kn[1], kn[2], kn[3]};
  *(float4*)(kkb + (size_t)j * C2 + c) = kp4;
  *(float4*)(kkb + (size_t)j * C2 + 256 + c) = kn4;
}

// kmean[c] = mean over k of kk[k][c]. 32 cols/block, 8 partials/col, coalesced.
__global__ void k_kmean(const float* __restrict__ kkb, float* __restrict__ kmean) {
  __shared__ float part[8][32];
  int cl = threadIdx.x & 31;
  int c = blockIdx.x * 32 + cl;
  int rc = threadIdx.x >> 5;  // 0..7
  float s = 0.f;
#pragma unroll 8
  for (int r = rc * 128; r < rc * 128 + 128; r++)
    s += kkb[(size_t)r * C2 + c];
  part[rc][cl] = s;
  __syncthreads();
  if (rc == 0) {
    float tsum = 0.f;
#pragma unroll
    for (int i = 0; i < 8; i++) tsum += part[i][cl];
    kmean[c] = tsum * (1.0f / 1024.0f);
  }
}

// kv_all = kk^T @ mnew / n, written TRANSPOSED into kvT[c][t] (256x512):
// kvT[c][t] = c<128 ? kv[t][c] : kv2[(t+256)&511][c-128]
__global__ __launch_bounds__(256) void k_kv(const float* __restrict__ kkb,
                                            const float* __restrict__ mnew,
                                            float* __restrict__ kvT) {
  __shared__ float Ks[32][64];
  __shared__ float Ms[32][64];
  int t = threadIdx.x;
  int t0 = blockIdx.x * 64, c0 = blockIdx.y * 64, kbase = blockIdx.z * 128;
  int cl4 = (t & 15) * 4, kr = t >> 4;
  int fr = (t & 15) * 4, fc = ((t >> 4) & 15) * 4;
  float acc[4][4] = {};
  for (int k0 = kbase; k0 < kbase + 128; k0 += 32) {
    __syncthreads();
#pragma unroll
    for (int ps = 0; ps < 2; ps++) {
      int kr2 = kr + ps * 16;
      *(float4*)&Ks[kr2][cl4] = *(const float4*)(kkb + (size_t)(k0 + kr2) * C2 + t0 + cl4);
      *(float4*)&Ms[kr2][cl4] = *(const float4*)(mnew + (size_t)(k0 + kr2) * CC + c0 + cl4);
    }
    __syncthreads();
#pragma unroll
    for (int kx = 0; kx < 32; kx++) {
      float4 a = *(const float4*)&Ks[kx][fr];
      float4 b = *(const float4*)&Ms[kx][fc];
      float av[4] = {a.x, a.y, a.z, a.w}, bv[4] = {b.x, b.y, b.z, b.w};
#pragma unroll
      for (int i = 0; i < 4; i++)
#pragma unroll
        for (int j = 0; j < 4; j++) acc[i][j] += av[i] * bv[j];
    }
  }
  const float sc = 1.0f / 32768.0f;
#pragma unroll
  for (int i = 0; i < 4; i++) {
    int tt = t0 + fr + i;
#pragma unroll
    for (int j = 0; j < 4; j++) {
      int c = c0 + fc + j;
      int drow = (c < 128) ? tt : ((tt + 256) & 511);
      atomicAdd(&kvT[(size_t)c * C2 + drow], acc[i][j] * sc);
    }
  }
}

// z = 1/(q_sim . kmean + eps), z2 = 1/(q_opp . kmean + eps). Wave per row.
__global__ void k_z(const float* __restrict__ xf, const float* __restrict__ rnorm,
                    const float* __restrict__ p, const float* __restrict__ kmean,
                    float* __restrict__ z, float* __restrict__ z2) {
  int wv = threadIdx.x >> 6, ln = threadIdx.x & 63;
  int row = blockIdx.x * 4 + wv;
  int c = ln * 4;
  float rn = rnorm[row];
  float4 v = *(const float4*)(xf + (size_t)row * CC + c);
  float4 p4 = *(const float4*)(p + c);
  float4 k0 = *(const float4*)(kmean + c);
  float4 k1 = *(const float4*)(kmean + 256 + c);
  float xv[4] = {v.x * rn, v.y * rn, v.z * rn, v.w * rn};
  float pv[4] = {p4.x, p4.y, p4.z, p4.w};
  float ka[4] = {k0.x, k0.y, k0.z, k0.w};
  float kb[4] = {k1.x, k1.y, k1.z, k1.w};
  float za = 0.0f, zb = 0.0f;
#pragma unroll
  for (int i = 0; i < 4; i++) {
    float qp = xv[i] > 0.0f ? fpow(xv[i], pv[i]) : 0.0f;
    float qn = (-xv[i]) > 0.0f ? fpow(-xv[i], pv[i]) : 0.0f;
    za += qp * ka[i] + qn * kb[i];
    zb += qn * ka[i] + qp * kb[i];
  }
  za = wredsum(za); zb = wredsum(zb);
  if (ln == 0) { z[row] = 1.0f / (za + 1e-6f); z2[row] = 1.0f / (zb + 1e-6f); }
}

// out = (xo + dwconv3x3(xo) + bias) * g, IN-PLACE on d_out per (b,ch) plane.
__global__ __launch_bounds__(256) void k_conv(float* __restrict__ out,
                                              const float* __restrict__ gt,
                                              const float* __restrict__ wc,
                                              const float* __restrict__ bc) {
  __shared__ float pl[64][64];
  int plane = blockIdx.x;
  int ch = plane & 255;
  int t = threadIdx.x;
  const float* src = out + (size_t)plane * HWHW;
#pragma unroll
  for (int ps = 0; ps < 4; ps++) {
    int i = ps * 1024 + t * 4;
    *(float4*)&pl[i >> 6][i & 63] = *(const float4*)(src + i);
  }
  float w[9];
#pragma unroll
  for (int i = 0; i < 9; i++) w[i] = wc[ch * 9 + i];
  float bias = bc[ch];
  __syncthreads();
#pragma unroll
  for (int ps = 0; ps < 16; ps++) {
    int pix = ps * 256 + t;
    int y = pix >> 6, x = pix & 63;
    float s = 0.0f;
#pragma unroll
    for (int dy = -1; dy <= 1; dy++) {
      int yy = y + dy;
      if (yy < 0 || yy > 63) continue;
#pragma unroll
      for (int dx = -1; dx <= 1; dx++) {
        int xx = x + dx;
        if (xx < 0 || xx > 63) continue;
        s += w[(dy + 1) * 3 + dx + 1] * pl[yy][xx];
      }
    }
    out[(size_t)plane * HWHW + pix] =
        (pl[y][x] + s + bias) * gt[(size_t)plane * HWHW + pix];
  }
}

extern "C" void kernel_launch(void* const* d_in, const int* in_sizes, int n_in,
                              void* d_out, int out_size, void* d_ws, size_t ws_size,
                              hipStream_t stream) {
  const float* x     = (const float*)d_in[0];
  const float* uw    = (const float*)d_in[1];
  const float* power = (const float*)d_in[2];
  const float* gw    = (const float*)d_in[3];
  const float* gb    = (const float*)d_in[4];
  const float* wc    = (const float*)d_in[5];
  const float* bcb   = (const float*)d_in[6];
  float* out   = (float*)d_out;
  float* score = out + (size_t)NN * CC;   // outputs concatenated: out, score
  float* ws = (float*)d_ws;

  float* xf    = ws + OFF_XF;
  float* gt    = ws + OFF_GT;
  float* rnorm = ws + OFF_RNORM;
  float* p     = ws + OFF_P;
  u16*   mn0h  = (u16*)(ws + OFF_MN0);
  u16*   mn0l  = (u16*)(ws + OFF_MN0 + 131072);
  float* mnew  = ws + OFF_MNEW;
  float* sums  = ws + OFF_SUMS;
  float* cnts  = ws + OFF_COUNTS;
  float* kmean = ws + OFF_KMEAN;
  float* kvT   = ws + OFF_KVBIG;
  float* z     = ws + OFF_Z;
  float* z2    = ws + OFF_Z2;
  int*   ind   = (int*)(ws + OFF_IND);
  float* kkbuf = ws + OFF_KK;
  u16*   gwh   = (u16*)(ws + OFF_GWS);
  u16*   gwl   = (u16*)(ws + OFF_GWS + 32768);
  u16*   kvh   = (u16*)(ws + OFF_KVS);
  u16*   kvl   = (u16*)(ws + OFF_KVS + 65536);

  k_prep<<<1, 256, 0, stream>>>(power, p);
  k_zero<<<1542, 256, 0, stream>>>(sums);  // sums..kvT contiguous
  k_transpose<<<dim3(128, 8, 8), dim3(32, 8), 0, stream>>>(x, xf);
  k_rownorm<<<8192, 256, 0, stream>>>(xf, rnorm);
  k_mnorm<<<256, 256, 0, stream>>>(uw, mn0h, mn0l);
  k_splitbuf<<<64, 256, 0, stream>>>(gw, gwh, gwl, 16384);       // gw 256x256
  k_score_mfma<<<dim3(256, 8), 256, 0, stream>>>(xf, rnorm, mn0h, mn0l, score);
  k_g_mfma<<<dim3(256, 2), 256, 0, stream>>>(xf, gwh, gwl, gb, gt);
  k_argmax<<<8192, 256, 0, stream>>>(score, ind);
  k_scatter<<<8192, 256, 0, stream>>>(xf, ind, sums, cnts);
  k_ema<<<256, 256, 0, stream>>>(uw, sums, cnts, p, mnew, kkbuf);
  k_kmean<<<16, 256, 0, stream>>>(kkbuf, kmean);
  k_kv<<<dim3(8, 4, 8), 256, 0, stream>>>(kkbuf, mnew, kvT);
  k_splitbuf<<<128, 256, 0, stream>>>(kvT, kvh, kvl, 32768);     // kvT 256x512
  k_z<<<8192, 256, 0, stream>>>(xf, rnorm, p, kmean, z, z2);
  k_x_mfma<<<dim3(256, 2), 256, 0, stream>>>(xf, rnorm, p, kvh, kvl, z, z2, out);
  k_conv<<<2048, 256, 0, stream>>>(out, gt, wc, bcb);
}